// Round 1
// baseline (1052.333 us; speedup 1.0000x reference)
//
#include <hip/hip_runtime.h>

// 3-layer GAT with edge attrs on MI355X.
// Pipeline: build dst-CSR (count -> scan -> scatter, self-loops appended with
// mean edge_attr), then per layer: GEMM (xp = h@W), per-node score reduce
// (s_src, s_dst), edge-coeff fold (c = We . a_e, 3xH), and a one-wave-per-node
// two-pass segment softmax + weighted gather.

constexpr int NN  = 50000;      // nodes
constexpr int NE  = 800000;     // original edges
constexpr int NET = NE + NN;    // edges incl. self loops

// ---------------------------------------------------------------- preprocess

__global__ __launch_bounds__(256) void k_count(const int* __restrict__ ei,
                                               const float* __restrict__ ea,
                                               int* __restrict__ cnt,
                                               float* __restrict__ sattr) {
  int e = blockIdx.x * 256 + threadIdx.x;
  if (e >= NE) return;
  int d = ei[NE + e];
  atomicAdd(&cnt[d], 1);
  atomicAdd(&sattr[3 * d + 0], ea[3 * (size_t)e + 0]);
  atomicAdd(&sattr[3 * d + 1], ea[3 * (size_t)e + 1]);
  atomicAdd(&sattr[3 * d + 2], ea[3 * (size_t)e + 2]);
}

// sattr -> mean in place (deg preserved in cnt)
__global__ __launch_bounds__(256) void k_mean(const int* __restrict__ cnt,
                                              float* __restrict__ sattr) {
  int n = blockIdx.x * 256 + threadIdx.x;
  if (n >= NN) return;
  float d = fmaxf((float)cnt[n], 1.0f);
  sattr[3 * n + 0] /= d;
  sattr[3 * n + 1] /= d;
  sattr[3 * n + 2] /= d;
}

// scan over (cnt[i]+1), 1024 elems per block
__global__ __launch_bounds__(256) void k_scan1(const int* __restrict__ cnt,
                                               int* __restrict__ bsum) {
  __shared__ int lds[256];
  int base = blockIdx.x * 1024;
  int s = 0;
  for (int i = 0; i < 4; i++) {
    int idx = base + threadIdx.x * 4 + i;
    if (idx < NN) s += cnt[idx] + 1;
  }
  lds[threadIdx.x] = s;
  __syncthreads();
  for (int off = 128; off > 0; off >>= 1) {
    if (threadIdx.x < off) lds[threadIdx.x] += lds[threadIdx.x + off];
    __syncthreads();
  }
  if (threadIdx.x == 0) bsum[blockIdx.x] = lds[0];
}

__global__ void k_scan2(int* bsum, int nblk) {
  int run = 0;
  for (int i = 0; i < nblk; i++) { int v = bsum[i]; bsum[i] = run; run += v; }
}

__global__ __launch_bounds__(256) void k_scan3(const int* __restrict__ cnt,
                                               const int* __restrict__ bsum,
                                               int* __restrict__ rowp,
                                               int* __restrict__ cursor) {
  __shared__ int lds[256];
  int t = threadIdx.x;
  int base = blockIdx.x * 1024;
  int v[4];
  int s = 0;
  for (int i = 0; i < 4; i++) {
    int idx = base + t * 4 + i;
    v[i] = (idx < NN) ? cnt[idx] + 1 : 0;
    s += v[i];
  }
  lds[t] = s;
  __syncthreads();
  // inclusive Hillis-Steele
  for (int off = 1; off < 256; off <<= 1) {
    int add = (t >= off) ? lds[t - off] : 0;
    __syncthreads();
    lds[t] += add;
    __syncthreads();
  }
  int p = bsum[blockIdx.x] + lds[t] - s;  // exclusive prefix for this thread
  for (int i = 0; i < 4; i++) {
    int idx = base + t * 4 + i;
    if (idx < NN) { rowp[idx] = p; cursor[idx] = p; }
    p += v[i];
  }
  if (blockIdx.x == 0 && t == 0) rowp[NN] = NET;
}

__global__ __launch_bounds__(256) void k_scatter(const int* __restrict__ ei,
                                                 const float* __restrict__ ea,
                                                 int* __restrict__ cursor,
                                                 int4* __restrict__ sorted) {
  int e = blockIdx.x * 256 + threadIdx.x;
  if (e >= NE) return;
  int s = ei[e];
  int d = ei[NE + e];
  int pos = atomicAdd(&cursor[d], 1);
  int4 r;
  r.x = s;
  r.y = __float_as_int(ea[3 * (size_t)e + 0]);
  r.z = __float_as_int(ea[3 * (size_t)e + 1]);
  r.w = __float_as_int(ea[3 * (size_t)e + 2]);
  sorted[pos] = r;
}

__global__ __launch_bounds__(256) void k_selfloop(const float* __restrict__ mean,
                                                  int* __restrict__ cursor,
                                                  int4* __restrict__ sorted) {
  int n = blockIdx.x * 256 + threadIdx.x;
  if (n >= NN) return;
  int pos = atomicAdd(&cursor[n], 1);
  int4 r;
  r.x = n;
  r.y = __float_as_int(mean[3 * n + 0]);
  r.z = __float_as_int(mean[3 * n + 1]);
  r.w = __float_as_int(mean[3 * n + 2]);
  sorted[pos] = r;
}

// ---------------------------------------------------------------- GEMM
// C[M x NC] = A[M x K] * W[K x NC]; K multiple of 16. 64x64 tile, 4x4/thread.
__global__ __launch_bounds__(256) void k_gemm(const float* __restrict__ A,
                                              const float* __restrict__ W,
                                              float* __restrict__ C,
                                              int M, int K, int NC) {
  __shared__ float As[64][17];
  __shared__ float Ws[16][65];
  int tx = threadIdx.x & 15, ty = threadIdx.x >> 4;
  int row0 = blockIdx.x * 64, col0 = blockIdx.y * 64;
  float acc[4][4] = {};
  for (int kk = 0; kk < K; kk += 16) {
    for (int i = 0; i < 4; i++) {
      int idx = threadIdx.x * 4 + i;
      int r = idx >> 4, c = idx & 15;
      int gr = row0 + r;
      As[r][c] = (gr < M) ? A[(size_t)gr * K + kk + c] : 0.f;
    }
    for (int i = 0; i < 4; i++) {
      int idx = threadIdx.x * 4 + i;
      int r = idx >> 6, c = idx & 63;
      int gc = col0 + c;
      Ws[r][c] = (gc < NC) ? W[(size_t)(kk + r) * NC + gc] : 0.f;
    }
    __syncthreads();
    for (int k = 0; k < 16; k++) {
      float a[4], w[4];
#pragma unroll
      for (int i = 0; i < 4; i++) a[i] = As[ty * 4 + i][k];
#pragma unroll
      for (int j = 0; j < 4; j++) w[j] = Ws[k][tx * 4 + j];
#pragma unroll
      for (int i = 0; i < 4; i++)
#pragma unroll
        for (int j = 0; j < 4; j++) acc[i][j] += a[i] * w[j];
    }
    __syncthreads();
  }
  for (int i = 0; i < 4; i++)
    for (int j = 0; j < 4; j++) {
      int r = row0 + ty * 4 + i, c = col0 + tx * 4 + j;
      if (r < M && c < NC) C[(size_t)r * NC + c] = acc[i][j];
    }
}

// ---------------------------------------------------------------- scores
// s_src[n,h] = sum_o xp[n,h*O+o]*a_src[h,o]; same for dst. One HO-group/node.
template <int H, int O>
__global__ __launch_bounds__(256) void k_scores(const float* __restrict__ xp,
                                                const float* __restrict__ a_src,
                                                const float* __restrict__ a_dst,
                                                float* __restrict__ ssrc,
                                                float* __restrict__ sdst) {
  constexpr int HO = H * O;
  constexpr int NPB = 256 / HO;
  int t = threadIdx.x;
  int j = t % HO;
  int n = blockIdx.x * NPB + t / HO;
  if (n >= NN) return;
  float v = xp[(size_t)n * HO + j];
  float ps = v * a_src[j];
  float pd = v * a_dst[j];
#pragma unroll
  for (int off = O / 2; off > 0; off >>= 1) {
    ps += __shfl_xor(ps, off);
    pd += __shfl_xor(pd, off);
  }
  if ((j & (O - 1)) == 0) {
    int h = j / O;
    ssrc[n * H + h] = ps;
    sdst[n * H + h] = pd;
  }
}

// c[d*H+h] = sum_o We[d, h*O+o] * a_e[h,o]
template <int H, int O>
__global__ void k_ce(const float* __restrict__ We, const float* __restrict__ ae,
                     float* __restrict__ c) {
  int t = threadIdx.x;
  if (t >= 3 * H) return;
  int d = t / H, h = t % H;
  float s = 0.f;
  for (int o = 0; o < O; o++) s += We[d * (H * O) + h * O + o] * ae[h * O + o];
  c[t] = s;
}

// ---------------------------------------------------------------- aggregate
// One wave per node. Pass 1: segment max of leaky-relu logits.
// Pass 2: p = exp(a-m); denom += p; acc += p * xp[src]. Epilogue: /denom +b, ELU.
template <int H, int O, bool DO_ELU>
__global__ __launch_bounds__(256) void k_agg(const int4* __restrict__ sorted,
                                             const int* __restrict__ rowp,
                                             const float* __restrict__ xp,
                                             const float* __restrict__ ssrc,
                                             const float* __restrict__ sdst,
                                             const float* __restrict__ ce,
                                             const float* __restrict__ bias,
                                             float* __restrict__ out) {
  constexpr int HO = H * O;
  constexpr int V = (HO >= 64) ? (HO / 64) : 1;
  int wave = threadIdx.x >> 6;
  int lane = threadIdx.x & 63;
  int n = blockIdx.x * 4 + wave;
  if (n >= NN) return;

  float sd[H], c0[H], c1[H], c2[H];
#pragma unroll
  for (int h = 0; h < H; h++) {
    sd[h] = sdst[n * H + h];
    c0[h] = ce[0 * H + h];
    c1[h] = ce[1 * H + h];
    c2[h] = ce[2 * H + h];
  }
  int rp0 = rowp[n], rp1 = rowp[n + 1];

  int h_lane = 0;
  if constexpr (HO >= 64) h_lane = (lane * V) / O;

  // pass 1: max
  float m[H];
#pragma unroll
  for (int h = 0; h < H; h++) m[h] = -1e30f;
  for (int j = rp0; j < rp1; j++) {
    int4 r = sorted[j];
    int s = r.x;
    float e0 = __int_as_float(r.y), e1 = __int_as_float(r.z), e2 = __int_as_float(r.w);
#pragma unroll
    for (int h = 0; h < H; h++) {
      float a = ssrc[s * H + h] + sd[h] + e0 * c0[h] + e1 * c1[h] + e2 * c2[h];
      a = a > 0.f ? a : 0.2f * a;
      m[h] = fmaxf(m[h], a);
    }
  }

  // pass 2: exp + accumulate
  float den[H];
#pragma unroll
  for (int h = 0; h < H; h++) den[h] = 0.f;
  float acc[V];
#pragma unroll
  for (int i = 0; i < V; i++) acc[i] = 0.f;

  for (int j = rp0; j < rp1; j++) {
    int4 r = sorted[j];
    int s = r.x;
    float e0 = __int_as_float(r.y), e1 = __int_as_float(r.z), e2 = __int_as_float(r.w);
    float p[H];
#pragma unroll
    for (int h = 0; h < H; h++) {
      float a = ssrc[s * H + h] + sd[h] + e0 * c0[h] + e1 * c1[h] + e2 * c2[h];
      a = a > 0.f ? a : 0.2f * a;
      p[h] = __expf(a - m[h]);
      den[h] += p[h];
    }
    if constexpr (HO >= 64) {
      const float* row = xp + (size_t)s * HO + lane * V;
      float pw = p[h_lane];
      if constexpr (V == 4) {
        float4 v4 = *(const float4*)row;
        acc[0] += pw * v4.x;
        acc[1] += pw * v4.y;
        acc[2] += pw * v4.z;
        acc[3] += pw * v4.w;
      } else {
        acc[0] += pw * row[0];
      }
    } else {
      if (lane < HO) acc[0] += p[lane / O] * xp[(size_t)s * HO + lane];
    }
  }

  if constexpr (HO >= 64) {
    float dinv = 1.0f / den[h_lane];
#pragma unroll
    for (int i = 0; i < V; i++) {
      int jc = lane * V + i;
      float v = acc[i] * dinv + bias[jc];
      if constexpr (DO_ELU) v = v > 0.f ? v : __expf(v) - 1.f;
      out[(size_t)n * HO + jc] = v;
    }
  } else {
    if (lane < HO) {
      float v = acc[0] / den[lane / O] + bias[lane];
      if constexpr (DO_ELU) v = v > 0.f ? v : __expf(v) - 1.f;
      out[(size_t)n * HO + lane] = v;
    }
  }
}

// ---------------------------------------------------------------- launch

extern "C" void kernel_launch(void* const* d_in, const int* in_sizes, int n_in,
                              void* d_out, int out_size, void* d_ws, size_t ws_size,
                              hipStream_t stream) {
  const float* x   = (const float*)d_in[0];
  const int*   ei  = (const int*)d_in[1];
  const float* ea  = (const float*)d_in[2];
  const float* W1  = (const float*)d_in[3];
  const float* as1 = (const float*)d_in[4];
  const float* ad1 = (const float*)d_in[5];
  const float* We1 = (const float*)d_in[6];
  const float* ae1 = (const float*)d_in[7];
  const float* b1  = (const float*)d_in[8];
  const float* W2  = (const float*)d_in[9];
  const float* as2 = (const float*)d_in[10];
  const float* ad2 = (const float*)d_in[11];
  const float* We2 = (const float*)d_in[12];
  const float* ae2 = (const float*)d_in[13];
  const float* b2  = (const float*)d_in[14];
  const float* W3  = (const float*)d_in[15];
  const float* as3 = (const float*)d_in[16];
  const float* ad3 = (const float*)d_in[17];
  const float* We3 = (const float*)d_in[18];
  const float* ae3 = (const float*)d_in[19];
  const float* b3  = (const float*)d_in[20];
  float* out = (float*)d_out;

  char* base = (char*)d_ws;
  size_t off = 0;
  auto get = [&](size_t bytes) -> char* {
    char* q = base + off;
    off += (bytes + 255) & ~(size_t)255;
    return q;
  };
  int*   cnt    = (int*)get((size_t)NN * 4);
  float* sattr  = (float*)get((size_t)NN * 12);
  int*   rowp   = (int*)get((size_t)(NN + 1) * 4);
  int*   cursor = (int*)get((size_t)NN * 4);
  int*   bsum   = (int*)get(256 * 4);
  int4*  sorted = (int4*)get((size_t)NET * 16);
  float* ssrc   = (float*)get((size_t)NN * 16);
  float* sdst   = (float*)get((size_t)NN * 16);
  float* ce     = (float*)get(256);
  float* bufA   = (float*)get((size_t)NN * 256 * 4);  // xp
  float* bufB   = (float*)get((size_t)NN * 256 * 4);  // layer output
  (void)ws_size; (void)in_sizes; (void)n_in; (void)out_size;

  hipMemsetAsync(cnt, 0, (size_t)NN * 4, stream);
  hipMemsetAsync(sattr, 0, (size_t)NN * 12, stream);

  const int EB = (NE + 255) / 256;   // 3125
  const int NB = (NN + 255) / 256;   // 196
  const int SB = (NN + 1023) / 1024; // 49

  k_count<<<EB, 256, 0, stream>>>(ei, ea, cnt, sattr);
  k_mean<<<NB, 256, 0, stream>>>(cnt, sattr);
  k_scan1<<<SB, 256, 0, stream>>>(cnt, bsum);
  k_scan2<<<1, 1, 0, stream>>>(bsum, SB);
  k_scan3<<<SB, 256, 0, stream>>>(cnt, bsum, rowp, cursor);
  k_scatter<<<EB, 256, 0, stream>>>(ei, ea, cursor, sorted);
  k_selfloop<<<NB, 256, 0, stream>>>(sattr, cursor, sorted);

  const int GR = (NN + 63) / 64;  // 782 row tiles
  const int AGB = (NN + 3) / 4;   // 12500 agg blocks

  // layer 1: 128 -> 4x64
  k_gemm<<<dim3(GR, 4), 256, 0, stream>>>(x, W1, bufA, NN, 128, 256);
  k_scores<4, 64><<<NN, 256, 0, stream>>>(bufA, as1, ad1, ssrc, sdst);
  k_ce<4, 64><<<1, 64, 0, stream>>>(We1, ae1, ce);
  k_agg<4, 64, true><<<AGB, 256, 0, stream>>>(sorted, rowp, bufA, ssrc, sdst, ce, b1, bufB);

  // layer 2: 256 -> 2x32
  k_gemm<<<dim3(GR, 1), 256, 0, stream>>>(bufB, W2, bufA, NN, 256, 64);
  k_scores<2, 32><<<(NN + 3) / 4, 256, 0, stream>>>(bufA, as2, ad2, ssrc, sdst);
  k_ce<2, 32><<<1, 64, 0, stream>>>(We2, ae2, ce);
  k_agg<2, 32, true><<<AGB, 256, 0, stream>>>(sorted, rowp, bufA, ssrc, sdst, ce, b2, bufB);

  // layer 3: 64 -> 1x16
  k_gemm<<<dim3(GR, 1), 256, 0, stream>>>(bufB, W3, bufA, NN, 64, 16);
  k_scores<1, 16><<<(NN + 15) / 16, 256, 0, stream>>>(bufA, as3, ad3, ssrc, sdst);
  k_ce<1, 16><<<1, 64, 0, stream>>>(We3, ae3, ce);
  k_agg<1, 16, false><<<AGB, 256, 0, stream>>>(sorted, rowp, bufA, ssrc, sdst, ce, b3, out);
}

// Round 3
// 677.009 us; speedup vs baseline: 1.5544x; 1.5544x over previous
//
#include <hip/hip_runtime.h>

// 3-layer GAT with edge attrs on MI355X.
// Round 2: identical to Round 1 (GPU acquisition timed out; re-submitting to
// get the measurement). Edge-parallel alpha precompute; k_agg restructured
// (lane-parallel max/exp + LDS-staged p, serial gather loop ~10 insts/edge);
// 128x64 fp32 GEMM; subwave groups for the 16-wide layer-3 aggregate.

constexpr int NN  = 50000;      // nodes
constexpr int NE  = 800000;     // original edges
constexpr int NET = NE + NN;    // edges incl. self loops

// ---------------------------------------------------------------- preprocess

__global__ __launch_bounds__(256) void k_count(const int* __restrict__ ei,
                                               const float* __restrict__ ea,
                                               int* __restrict__ cnt,
                                               float* __restrict__ sattr) {
  int e = blockIdx.x * 256 + threadIdx.x;
  if (e >= NE) return;
  int d = ei[NE + e];
  atomicAdd(&cnt[d], 1);
  atomicAdd(&sattr[3 * d + 0], ea[3 * (size_t)e + 0]);
  atomicAdd(&sattr[3 * d + 1], ea[3 * (size_t)e + 1]);
  atomicAdd(&sattr[3 * d + 2], ea[3 * (size_t)e + 2]);
}

__global__ __launch_bounds__(256) void k_mean(const int* __restrict__ cnt,
                                              float* __restrict__ sattr) {
  int n = blockIdx.x * 256 + threadIdx.x;
  if (n >= NN) return;
  float d = fmaxf((float)cnt[n], 1.0f);
  sattr[3 * n + 0] /= d;
  sattr[3 * n + 1] /= d;
  sattr[3 * n + 2] /= d;
}

__global__ __launch_bounds__(256) void k_scan1(const int* __restrict__ cnt,
                                               int* __restrict__ bsum) {
  __shared__ int lds[256];
  int base = blockIdx.x * 1024;
  int s = 0;
  for (int i = 0; i < 4; i++) {
    int idx = base + threadIdx.x * 4 + i;
    if (idx < NN) s += cnt[idx] + 1;
  }
  lds[threadIdx.x] = s;
  __syncthreads();
  for (int off = 128; off > 0; off >>= 1) {
    if (threadIdx.x < off) lds[threadIdx.x] += lds[threadIdx.x + off];
    __syncthreads();
  }
  if (threadIdx.x == 0) bsum[blockIdx.x] = lds[0];
}

__global__ void k_scan2(int* bsum, int nblk) {
  int run = 0;
  for (int i = 0; i < nblk; i++) { int v = bsum[i]; bsum[i] = run; run += v; }
}

__global__ __launch_bounds__(256) void k_scan3(const int* __restrict__ cnt,
                                               const int* __restrict__ bsum,
                                               int* __restrict__ rowp,
                                               int* __restrict__ cursor) {
  __shared__ int lds[256];
  int t = threadIdx.x;
  int base = blockIdx.x * 1024;
  int v[4];
  int s = 0;
  for (int i = 0; i < 4; i++) {
    int idx = base + t * 4 + i;
    v[i] = (idx < NN) ? cnt[idx] + 1 : 0;
    s += v[i];
  }
  lds[t] = s;
  __syncthreads();
  for (int off = 1; off < 256; off <<= 1) {
    int add = (t >= off) ? lds[t - off] : 0;
    __syncthreads();
    lds[t] += add;
    __syncthreads();
  }
  int p = bsum[blockIdx.x] + lds[t] - s;
  for (int i = 0; i < 4; i++) {
    int idx = base + t * 4 + i;
    if (idx < NN) { rowp[idx] = p; cursor[idx] = p; }
    p += v[i];
  }
  if (blockIdx.x == 0 && t == 0) rowp[NN] = NET;
}

__global__ __launch_bounds__(256) void k_scatter(const int* __restrict__ ei,
                                                 const float* __restrict__ ea,
                                                 int* __restrict__ cursor,
                                                 int4* __restrict__ sorted,
                                                 int* __restrict__ srcid,
                                                 int* __restrict__ dstid) {
  int e = blockIdx.x * 256 + threadIdx.x;
  if (e >= NE) return;
  int s = ei[e];
  int d = ei[NE + e];
  int pos = atomicAdd(&cursor[d], 1);
  int4 r;
  r.x = s;
  r.y = __float_as_int(ea[3 * (size_t)e + 0]);
  r.z = __float_as_int(ea[3 * (size_t)e + 1]);
  r.w = __float_as_int(ea[3 * (size_t)e + 2]);
  sorted[pos] = r;
  srcid[pos] = s;
  dstid[pos] = d;
}

__global__ __launch_bounds__(256) void k_selfloop(const float* __restrict__ mean,
                                                  int* __restrict__ cursor,
                                                  int4* __restrict__ sorted,
                                                  int* __restrict__ srcid,
                                                  int* __restrict__ dstid) {
  int n = blockIdx.x * 256 + threadIdx.x;
  if (n >= NN) return;
  int pos = atomicAdd(&cursor[n], 1);
  int4 r;
  r.x = n;
  r.y = __float_as_int(mean[3 * n + 0]);
  r.z = __float_as_int(mean[3 * n + 1]);
  r.w = __float_as_int(mean[3 * n + 2]);
  sorted[pos] = r;
  srcid[pos] = n;
  dstid[pos] = n;
}

// ---------------------------------------------------------------- GEMM
// BM=128 BN=64 BK=16, 256 threads, 8x4 per thread.
__global__ __launch_bounds__(256) void k_gemm2(const float* __restrict__ A,
                                               const float* __restrict__ W,
                                               float* __restrict__ C,
                                               int M, int K, int NC) {
  __shared__ float As[128][17];
  __shared__ float Ws[16][68];
  const int t = threadIdx.x;
  const int tx = t & 15, ty = t >> 4;
  const int row0 = blockIdx.x * 128, col0 = blockIdx.y * 64;
  float acc[8][4] = {};
  const int ar = t >> 2, ac = (t & 3) * 4;     // A stage: rows ar, ar+64
  const int wr = t >> 4, wc = (t & 15) * 4;    // W stage
  for (int kk = 0; kk < K; kk += 16) {
#pragma unroll
    for (int half = 0; half < 2; half++) {
      int r = ar + half * 64;
      int gr = row0 + r;
      float4 v = make_float4(0.f, 0.f, 0.f, 0.f);
      if (gr < M) v = *(const float4*)(A + (size_t)gr * K + kk + ac);
      As[r][ac] = v.x; As[r][ac + 1] = v.y; As[r][ac + 2] = v.z; As[r][ac + 3] = v.w;
    }
    *(float4*)&Ws[wr][wc] = *(const float4*)(W + (size_t)(kk + wr) * NC + col0 + wc);
    __syncthreads();
#pragma unroll
    for (int k = 0; k < 16; k++) {
      float a[8];
#pragma unroll
      for (int i = 0; i < 8; i++) a[i] = As[ty * 8 + i][k];
      float4 wv = *(const float4*)&Ws[k][tx * 4];
#pragma unroll
      for (int i = 0; i < 8; i++) {
        acc[i][0] += a[i] * wv.x;
        acc[i][1] += a[i] * wv.y;
        acc[i][2] += a[i] * wv.z;
        acc[i][3] += a[i] * wv.w;
      }
    }
    __syncthreads();
  }
#pragma unroll
  for (int i = 0; i < 8; i++) {
    int r = row0 + ty * 8 + i;
    if (r < M) *(float4*)(C + (size_t)r * NC + col0 + tx * 4) = *(float4*)acc[i];
  }
}

// NC=16, K=64 special GEMM: 16 nodes per block, LDS-staged.
__global__ __launch_bounds__(256) void k_gemm16(const float* __restrict__ A,
                                                const float* __restrict__ W,
                                                float* __restrict__ C) {
  __shared__ float hs[16][68];
  __shared__ float Ws[64][16];
  int t = threadIdx.x;
  int n0 = blockIdx.x * 16;
  {
    int r = t >> 2, c = (t & 3) * 4;
    *(float4*)&Ws[r][c] = *(const float4*)(W + r * 16 + c);
  }
  {
    int nl = t >> 4, c = (t & 15) * 4;
    int gn = n0 + nl;
    float4 v = make_float4(0.f, 0.f, 0.f, 0.f);
    if (gn < NN) v = *(const float4*)(A + (size_t)gn * 64 + c);
    *(float4*)&hs[nl][c] = v;
  }
  __syncthreads();
  int nl = t >> 4, col = t & 15;
  float acc = 0.f;
#pragma unroll
  for (int k = 0; k < 64; k++) acc += hs[nl][k] * Ws[k][col];
  int gn = n0 + nl;
  if (gn < NN) C[(size_t)gn * 16 + col] = acc;
}

// ---------------------------------------------------------------- scores
template <int H, int O>
__global__ __launch_bounds__(256) void k_scores(const float* __restrict__ xp,
                                                const float* __restrict__ a_src,
                                                const float* __restrict__ a_dst,
                                                float* __restrict__ ssrc,
                                                float* __restrict__ sdst) {
  constexpr int HO = H * O;
  constexpr int NPB = 256 / HO;
  int t = threadIdx.x;
  int j = t % HO;
  int n = blockIdx.x * NPB + t / HO;
  if (n >= NN) return;
  float v = xp[(size_t)n * HO + j];
  float ps = v * a_src[j];
  float pd = v * a_dst[j];
#pragma unroll
  for (int off = O / 2; off > 0; off >>= 1) {
    ps += __shfl_xor(ps, off);
    pd += __shfl_xor(pd, off);
  }
  if ((j & (O - 1)) == 0) {
    int h = j / O;
    ssrc[n * H + h] = ps;
    sdst[n * H + h] = pd;
  }
}

template <int H, int O>
__global__ void k_ce(const float* __restrict__ We, const float* __restrict__ ae,
                     float* __restrict__ c) {
  int t = threadIdx.x;
  if (t >= 3 * H) return;
  int d = t / H, h = t % H;
  float s = 0.f;
  for (int o = 0; o < O; o++) s += We[d * (H * O) + h * O + o] * ae[h * O + o];
  c[t] = s;
}

// ---------------------------------------------------------------- alpha
// Edge-parallel leaky logits: alpha[e,h] = leaky(ssrc[s]+sdst[d]+e.ce).
template <int H>
__global__ __launch_bounds__(256) void k_alpha(const int4* __restrict__ sorted,
                                               const int* __restrict__ dstid,
                                               const float* __restrict__ ssrc,
                                               const float* __restrict__ sdst,
                                               const float* __restrict__ ce,
                                               float* __restrict__ alpha) {
  int e = blockIdx.x * 256 + threadIdx.x;
  if (e >= NET) return;
  int4 r = sorted[e];
  int s = r.x, d = dstid[e];
  float e0 = __int_as_float(r.y), e1 = __int_as_float(r.z), e2 = __int_as_float(r.w);
  float a[H];
  if constexpr (H == 4) {
    float4 sv = *(const float4*)(ssrc + 4 * (size_t)s);
    float4 dv = *(const float4*)(sdst + 4 * (size_t)d);
    a[0] = sv.x + dv.x; a[1] = sv.y + dv.y; a[2] = sv.z + dv.z; a[3] = sv.w + dv.w;
  } else if constexpr (H == 2) {
    float2 sv = *(const float2*)(ssrc + 2 * (size_t)s);
    float2 dv = *(const float2*)(sdst + 2 * (size_t)d);
    a[0] = sv.x + dv.x; a[1] = sv.y + dv.y;
  } else {
    a[0] = ssrc[s] + sdst[d];
  }
#pragma unroll
  for (int h = 0; h < H; h++) {
    float v = a[h] + e0 * ce[h] + e1 * ce[H + h] + e2 * ce[2 * H + h];
    a[h] = v > 0.f ? v : 0.2f * v;
  }
  if constexpr (H == 4) {
    *(float4*)(alpha + 4 * (size_t)e) = make_float4(a[0], a[1], a[2], a[3]);
  } else if constexpr (H == 2) {
    *(float2*)(alpha + 2 * (size_t)e) = make_float2(a[0], a[1]);
  } else {
    alpha[e] = a[0];
  }
}

// ---------------------------------------------------------------- aggregate
// One wave per node, HO = 64*V columns. Lane-parallel max + exp (p staged in
// LDS per 64-edge chunk), serial gather-accumulate over the chunk.
template <int H, int V, bool DO_ELU>
__global__ __launch_bounds__(256) void k_agg2(const int* __restrict__ srcid,
                                              const float* __restrict__ alpha,
                                              const int* __restrict__ rowp,
                                              const float* __restrict__ xp,
                                              const float* __restrict__ bias,
                                              float* __restrict__ out) {
  constexpr int HO = 64 * V;
  constexpr int OC = HO / H;
  __shared__ float lds_p[4][64][H];
  __shared__ int lds_s[4][64];
  const int wave = threadIdx.x >> 6, lane = threadIdx.x & 63;
  const int n = blockIdx.x * 4 + wave;
  if (n >= NN) return;
  const int rp0 = rowp[n], rp1 = rowp[n + 1];
  const int h_lane = (lane * V) / OC;

  float m[H];
#pragma unroll
  for (int h = 0; h < H; h++) m[h] = -1e30f;
  for (int j = rp0 + lane; j < rp1; j += 64) {
    float a[H];
    if constexpr (H == 4) {
      float4 v = ((const float4*)alpha)[j];
      a[0] = v.x; a[1] = v.y; a[2] = v.z; a[3] = v.w;
    } else if constexpr (H == 2) {
      float2 v = ((const float2*)alpha)[j];
      a[0] = v.x; a[1] = v.y;
    } else {
      a[0] = alpha[j];
    }
#pragma unroll
    for (int h = 0; h < H; h++) m[h] = fmaxf(m[h], a[h]);
  }
#pragma unroll
  for (int off = 32; off > 0; off >>= 1)
#pragma unroll
    for (int h = 0; h < H; h++) m[h] = fmaxf(m[h], __shfl_xor(m[h], off));

  float den[H];
#pragma unroll
  for (int h = 0; h < H; h++) den[h] = 0.f;
  float acc[V];
#pragma unroll
  for (int i = 0; i < V; i++) acc[i] = 0.f;

  for (int c0 = rp0; c0 < rp1; c0 += 64) {
    const int cnt = min(64, rp1 - c0);
    if (lane < cnt) {
      const int j = c0 + lane;
      float a[H];
      if constexpr (H == 4) {
        float4 v = ((const float4*)alpha)[j];
        a[0] = v.x; a[1] = v.y; a[2] = v.z; a[3] = v.w;
      } else if constexpr (H == 2) {
        float2 v = ((const float2*)alpha)[j];
        a[0] = v.x; a[1] = v.y;
      } else {
        a[0] = alpha[j];
      }
#pragma unroll
      for (int h = 0; h < H; h++) {
        float p = __expf(a[h] - m[h]);
        den[h] += p;
        lds_p[wave][lane][h] = p;
      }
      lds_s[wave][lane] = srcid[j];
    }
    for (int c = 0; c < cnt; c++) {
      const float pw = lds_p[wave][c][h_lane];
      const int s = lds_s[wave][c];
      const float* row = xp + (size_t)s * HO + lane * V;
      if constexpr (V == 4) {
        float4 v = *(const float4*)row;
        acc[0] += pw * v.x; acc[1] += pw * v.y; acc[2] += pw * v.z; acc[3] += pw * v.w;
      } else {
        acc[0] += pw * row[0];
      }
    }
  }
#pragma unroll
  for (int off = 32; off > 0; off >>= 1)
#pragma unroll
    for (int h = 0; h < H; h++) den[h] += __shfl_xor(den[h], off);

  const float dinv = 1.f / den[h_lane];
#pragma unroll
  for (int i = 0; i < V; i++) {
    const int jc = lane * V + i;
    float v = acc[i] * dinv + bias[jc];
    if constexpr (DO_ELU) v = v > 0.f ? v : __expf(v) - 1.f;
    out[(size_t)n * HO + jc] = v;
  }
}

// Layer-3 aggregate: HO=16, H=1 — 16-lane groups, 16 nodes per block.
__global__ __launch_bounds__(256) void k_agg3(const int* __restrict__ srcid,
                                              const float* __restrict__ alpha,
                                              const int* __restrict__ rowp,
                                              const float* __restrict__ xp,
                                              const float* __restrict__ bias,
                                              float* __restrict__ out) {
  __shared__ float lds_p[16][16];
  __shared__ int lds_s[16][16];
  int t = threadIdx.x, g = t >> 4, gl = t & 15;
  int n = blockIdx.x * 16 + g;
  if (n >= NN) return;
  int rp0 = rowp[n], rp1 = rowp[n + 1];
  float m = -1e30f;
  for (int j = rp0 + gl; j < rp1; j += 16) m = fmaxf(m, alpha[j]);
#pragma unroll
  for (int off = 8; off > 0; off >>= 1) m = fmaxf(m, __shfl_xor(m, off));
  float den = 0.f, acc = 0.f;
  for (int c0 = rp0; c0 < rp1; c0 += 16) {
    int cnt = min(16, rp1 - c0);
    if (gl < cnt) {
      float p = __expf(alpha[c0 + gl] - m);
      den += p;
      lds_p[g][gl] = p;
      lds_s[g][gl] = srcid[c0 + gl];
    }
    for (int c = 0; c < cnt; c++)
      acc += lds_p[g][c] * xp[(size_t)lds_s[g][c] * 16 + gl];
  }
#pragma unroll
  for (int off = 8; off > 0; off >>= 1) den += __shfl_xor(den, off);
  out[(size_t)n * 16 + gl] = acc / den + bias[gl];
}

// ---------------------------------------------------------------- launch

extern "C" void kernel_launch(void* const* d_in, const int* in_sizes, int n_in,
                              void* d_out, int out_size, void* d_ws, size_t ws_size,
                              hipStream_t stream) {
  const float* x   = (const float*)d_in[0];
  const int*   ei  = (const int*)d_in[1];
  const float* ea  = (const float*)d_in[2];
  const float* W1  = (const float*)d_in[3];
  const float* as1 = (const float*)d_in[4];
  const float* ad1 = (const float*)d_in[5];
  const float* We1 = (const float*)d_in[6];
  const float* ae1 = (const float*)d_in[7];
  const float* b1  = (const float*)d_in[8];
  const float* W2  = (const float*)d_in[9];
  const float* as2 = (const float*)d_in[10];
  const float* ad2 = (const float*)d_in[11];
  const float* We2 = (const float*)d_in[12];
  const float* ae2 = (const float*)d_in[13];
  const float* b2  = (const float*)d_in[14];
  const float* W3  = (const float*)d_in[15];
  const float* as3 = (const float*)d_in[16];
  const float* ad3 = (const float*)d_in[17];
  const float* We3 = (const float*)d_in[18];
  const float* ae3 = (const float*)d_in[19];
  const float* b3  = (const float*)d_in[20];
  float* out = (float*)d_out;

  char* base = (char*)d_ws;
  size_t off = 0;
  auto get = [&](size_t bytes) -> char* {
    char* q = base + off;
    off += (bytes + 255) & ~(size_t)255;
    return q;
  };
  int*   cnt    = (int*)get((size_t)NN * 4);
  float* sattr  = (float*)get((size_t)NN * 12);
  int*   rowp   = (int*)get((size_t)(NN + 1) * 4);
  int*   cursor = (int*)get((size_t)NN * 4);
  int*   bsum   = (int*)get(256 * 4);
  int4*  sorted = (int4*)get((size_t)NET * 16);
  int*   srcid  = (int*)get((size_t)NET * 4);
  int*   dstid  = (int*)get((size_t)NET * 4);
  float* alpha  = (float*)get((size_t)NET * 16);  // up to H=4
  float* ssrc   = (float*)get((size_t)NN * 16);
  float* sdst   = (float*)get((size_t)NN * 16);
  float* ce     = (float*)get(256);
  float* bufA   = (float*)get((size_t)NN * 256 * 4);
  float* bufB   = (float*)get((size_t)NN * 256 * 4);
  (void)ws_size; (void)in_sizes; (void)n_in; (void)out_size;

  hipMemsetAsync(cnt, 0, (size_t)NN * 4, stream);
  hipMemsetAsync(sattr, 0, (size_t)NN * 12, stream);

  const int EB = (NE + 255) / 256;
  const int NB = (NN + 255) / 256;
  const int SB = (NN + 1023) / 1024;
  const int AB = (NET + 255) / 256;

  k_count<<<EB, 256, 0, stream>>>(ei, ea, cnt, sattr);
  k_mean<<<NB, 256, 0, stream>>>(cnt, sattr);
  k_scan1<<<SB, 256, 0, stream>>>(cnt, bsum);
  k_scan2<<<1, 1, 0, stream>>>(bsum, SB);
  k_scan3<<<SB, 256, 0, stream>>>(cnt, bsum, rowp, cursor);
  k_scatter<<<EB, 256, 0, stream>>>(ei, ea, cursor, sorted, srcid, dstid);
  k_selfloop<<<NB, 256, 0, stream>>>(sattr, cursor, sorted, srcid, dstid);

  const int GR = (NN + 127) / 128;  // 391
  const int AGB = (NN + 3) / 4;     // 12500

  // layer 1: 128 -> 4x64
  k_gemm2<<<dim3(GR, 4), 256, 0, stream>>>(x, W1, bufA, NN, 128, 256);
  k_scores<4, 64><<<NN, 256, 0, stream>>>(bufA, as1, ad1, ssrc, sdst);
  k_ce<4, 64><<<1, 64, 0, stream>>>(We1, ae1, ce);
  k_alpha<4><<<AB, 256, 0, stream>>>(sorted, dstid, ssrc, sdst, ce, alpha);
  k_agg2<4, 4, true><<<AGB, 256, 0, stream>>>(srcid, alpha, rowp, bufA, b1, bufB);

  // layer 2: 256 -> 2x32
  k_gemm2<<<dim3(GR, 1), 256, 0, stream>>>(bufB, W2, bufA, NN, 256, 64);
  k_scores<2, 32><<<(NN + 3) / 4, 256, 0, stream>>>(bufA, as2, ad2, ssrc, sdst);
  k_ce<2, 32><<<1, 64, 0, stream>>>(We2, ae2, ce);
  k_alpha<2><<<AB, 256, 0, stream>>>(sorted, dstid, ssrc, sdst, ce, alpha);
  k_agg2<2, 1, true><<<AGB, 256, 0, stream>>>(srcid, alpha, rowp, bufA, b2, bufB);

  // layer 3: 64 -> 1x16
  k_gemm16<<<(NN + 15) / 16, 256, 0, stream>>>(bufB, W3, bufA);
  k_scores<1, 16><<<(NN + 15) / 16, 256, 0, stream>>>(bufA, as3, ad3, ssrc, sdst);
  k_ce<1, 16><<<1, 64, 0, stream>>>(We3, ae3, ce);
  k_alpha<1><<<AB, 256, 0, stream>>>(sorted, dstid, ssrc, sdst, ce, alpha);
  k_agg3<<<(NN + 15) / 16, 256, 0, stream>>>(srcid, alpha, rowp, bufA, b3, out);
}

// Round 4
// 537.233 us; speedup vs baseline: 1.9588x; 1.2602x over previous
//
#include <hip/hip_runtime.h>

// 3-layer GAT with edge attrs on MI355X.
// Round 3: preprocessing de-atomized (count keeps 1 int atomic/edge; mean-attr
// + self-loop via post-scatter segment sum, no float atomics); alpha fused
// into the aggregate kernels (recomputed in max+exp passes from sorted[] and
// the L2-resident ssrc table) — k_alpha/k_mean/k_selfloop dispatches, alpha
// buffer, and srcid/dstid arrays eliminated.

constexpr int NN  = 50000;      // nodes
constexpr int NE  = 800000;     // original edges
constexpr int NET = NE + NN;    // edges incl. self loops

// ---------------------------------------------------------------- preprocess

__global__ __launch_bounds__(256) void k_count(const int* __restrict__ ei,
                                               int* __restrict__ cnt) {
  int e = blockIdx.x * 256 + threadIdx.x;
  if (e >= NE) return;
  atomicAdd(&cnt[ei[NE + e]], 1);
}

__global__ __launch_bounds__(256) void k_scan1(const int* __restrict__ cnt,
                                               int* __restrict__ bsum) {
  __shared__ int lds[256];
  int base = blockIdx.x * 1024;
  int s = 0;
  for (int i = 0; i < 4; i++) {
    int idx = base + threadIdx.x * 4 + i;
    if (idx < NN) s += cnt[idx] + 1;
  }
  lds[threadIdx.x] = s;
  __syncthreads();
  for (int off = 128; off > 0; off >>= 1) {
    if (threadIdx.x < off) lds[threadIdx.x] += lds[threadIdx.x + off];
    __syncthreads();
  }
  if (threadIdx.x == 0) bsum[blockIdx.x] = lds[0];
}

__global__ void k_scan2(int* bsum, int nblk) {
  int run = 0;
  for (int i = 0; i < nblk; i++) { int v = bsum[i]; bsum[i] = run; run += v; }
}

__global__ __launch_bounds__(256) void k_scan3(const int* __restrict__ cnt,
                                               const int* __restrict__ bsum,
                                               int* __restrict__ rowp,
                                               int* __restrict__ cursor) {
  __shared__ int lds[256];
  int t = threadIdx.x;
  int base = blockIdx.x * 1024;
  int v[4];
  int s = 0;
  for (int i = 0; i < 4; i++) {
    int idx = base + t * 4 + i;
    v[i] = (idx < NN) ? cnt[idx] + 1 : 0;
    s += v[i];
  }
  lds[t] = s;
  __syncthreads();
  for (int off = 1; off < 256; off <<= 1) {
    int add = (t >= off) ? lds[t - off] : 0;
    __syncthreads();
    lds[t] += add;
    __syncthreads();
  }
  int p = bsum[blockIdx.x] + lds[t] - s;
  for (int i = 0; i < 4; i++) {
    int idx = base + t * 4 + i;
    if (idx < NN) { rowp[idx] = p; cursor[idx] = p; }
    p += v[i];
  }
  if (blockIdx.x == 0 && t == 0) rowp[NN] = NET;
}

__global__ __launch_bounds__(256) void k_scatter(const int* __restrict__ ei,
                                                 const float* __restrict__ ea,
                                                 int* __restrict__ cursor,
                                                 int4* __restrict__ sorted) {
  int e = blockIdx.x * 256 + threadIdx.x;
  if (e >= NE) return;
  int s = ei[e];
  int d = ei[NE + e];
  int pos = atomicAdd(&cursor[d], 1);
  int4 r;
  r.x = s;
  r.y = __float_as_int(ea[3 * (size_t)e + 0]);
  r.z = __float_as_int(ea[3 * (size_t)e + 1]);
  r.w = __float_as_int(ea[3 * (size_t)e + 2]);
  sorted[pos] = r;
}

// Per-node segment sum of edge_attr over real edges -> mean; write self-loop
// record at rowp[n+1]-1. 16-lane group per node, no atomics.
__global__ __launch_bounds__(256) void k_segloop(const int* __restrict__ rowp,
                                                 int4* __restrict__ sorted) {
  int t = threadIdx.x, g = t >> 4, gl = t & 15;
  int n = blockIdx.x * 16 + g;
  if (n >= NN) return;
  int rp0 = rowp[n], rp1e = rowp[n + 1] - 1;  // real edges: [rp0, rp1e)
  float s0 = 0.f, s1 = 0.f, s2 = 0.f;
  for (int j = rp0 + gl; j < rp1e; j += 16) {
    int4 r = sorted[j];
    s0 += __int_as_float(r.y);
    s1 += __int_as_float(r.z);
    s2 += __int_as_float(r.w);
  }
#pragma unroll
  for (int off = 8; off > 0; off >>= 1) {
    s0 += __shfl_xor(s0, off);
    s1 += __shfl_xor(s1, off);
    s2 += __shfl_xor(s2, off);
  }
  if (gl == 0) {
    float inv = 1.f / fmaxf((float)(rp1e - rp0), 1.f);
    int4 r;
    r.x = n;
    r.y = __float_as_int(s0 * inv);
    r.z = __float_as_int(s1 * inv);
    r.w = __float_as_int(s2 * inv);
    sorted[rp1e] = r;
  }
}

// ---------------------------------------------------------------- GEMM
// BM=128 BN=64 BK=16, 256 threads, 8x4 per thread.
__global__ __launch_bounds__(256) void k_gemm2(const float* __restrict__ A,
                                               const float* __restrict__ W,
                                               float* __restrict__ C,
                                               int M, int K, int NC) {
  __shared__ float As[128][17];
  __shared__ float Ws[16][68];
  const int t = threadIdx.x;
  const int tx = t & 15, ty = t >> 4;
  const int row0 = blockIdx.x * 128, col0 = blockIdx.y * 64;
  float acc[8][4] = {};
  const int ar = t >> 2, ac = (t & 3) * 4;
  const int wr = t >> 4, wc = (t & 15) * 4;
  for (int kk = 0; kk < K; kk += 16) {
#pragma unroll
    for (int half = 0; half < 2; half++) {
      int r = ar + half * 64;
      int gr = row0 + r;
      float4 v = make_float4(0.f, 0.f, 0.f, 0.f);
      if (gr < M) v = *(const float4*)(A + (size_t)gr * K + kk + ac);
      As[r][ac] = v.x; As[r][ac + 1] = v.y; As[r][ac + 2] = v.z; As[r][ac + 3] = v.w;
    }
    *(float4*)&Ws[wr][wc] = *(const float4*)(W + (size_t)(kk + wr) * NC + col0 + wc);
    __syncthreads();
#pragma unroll
    for (int k = 0; k < 16; k++) {
      float a[8];
#pragma unroll
      for (int i = 0; i < 8; i++) a[i] = As[ty * 8 + i][k];
      float4 wv = *(const float4*)&Ws[k][tx * 4];
#pragma unroll
      for (int i = 0; i < 8; i++) {
        acc[i][0] += a[i] * wv.x;
        acc[i][1] += a[i] * wv.y;
        acc[i][2] += a[i] * wv.z;
        acc[i][3] += a[i] * wv.w;
      }
    }
    __syncthreads();
  }
#pragma unroll
  for (int i = 0; i < 8; i++) {
    int r = row0 + ty * 8 + i;
    if (r < M) *(float4*)(C + (size_t)r * NC + col0 + tx * 4) = *(float4*)acc[i];
  }
}

// NC=16, K=64 special GEMM: 16 nodes per block, LDS-staged.
__global__ __launch_bounds__(256) void k_gemm16(const float* __restrict__ A,
                                                const float* __restrict__ W,
                                                float* __restrict__ C) {
  __shared__ float hs[16][68];
  __shared__ float Ws[64][16];
  int t = threadIdx.x;
  int n0 = blockIdx.x * 16;
  {
    int r = t >> 2, c = (t & 3) * 4;
    *(float4*)&Ws[r][c] = *(const float4*)(W + r * 16 + c);
  }
  {
    int nl = t >> 4, c = (t & 15) * 4;
    int gn = n0 + nl;
    float4 v = make_float4(0.f, 0.f, 0.f, 0.f);
    if (gn < NN) v = *(const float4*)(A + (size_t)gn * 64 + c);
    *(float4*)&hs[nl][c] = v;
  }
  __syncthreads();
  int nl = t >> 4, col = t & 15;
  float acc = 0.f;
#pragma unroll
  for (int k = 0; k < 64; k++) acc += hs[nl][k] * Ws[k][col];
  int gn = n0 + nl;
  if (gn < NN) C[(size_t)gn * 16 + col] = acc;
}

// ---------------------------------------------------------------- scores
template <int H, int O>
__global__ __launch_bounds__(256) void k_scores(const float* __restrict__ xp,
                                                const float* __restrict__ a_src,
                                                const float* __restrict__ a_dst,
                                                float* __restrict__ ssrc,
                                                float* __restrict__ sdst) {
  constexpr int HO = H * O;
  constexpr int NPB = 256 / HO;
  int t = threadIdx.x;
  int j = t % HO;
  int n = blockIdx.x * NPB + t / HO;
  if (n >= NN) return;
  float v = xp[(size_t)n * HO + j];
  float ps = v * a_src[j];
  float pd = v * a_dst[j];
#pragma unroll
  for (int off = O / 2; off > 0; off >>= 1) {
    ps += __shfl_xor(ps, off);
    pd += __shfl_xor(pd, off);
  }
  if ((j & (O - 1)) == 0) {
    int h = j / O;
    ssrc[n * H + h] = ps;
    sdst[n * H + h] = pd;
  }
}

template <int H, int O>
__global__ void k_ce(const float* __restrict__ We, const float* __restrict__ ae,
                     float* __restrict__ c) {
  int t = threadIdx.x;
  if (t >= 3 * H) return;
  int d = t / H, h = t % H;
  float s = 0.f;
  for (int o = 0; o < O; o++) s += We[d * (H * O) + h * O + o] * ae[h * O + o];
  c[t] = s;
}

// ---------------------------------------------------------------- aggregate
// One wave per node. Alpha computed in-kernel (sdst is wave-uniform; ssrc is an
// L2-resident gather). Pass 1: max. Pass 2 per 64-chunk: exp -> LDS p, then
// serial gather-accumulate.
template <int H, int V, bool DO_ELU>
__global__ __launch_bounds__(256) void k_agg2(const int4* __restrict__ sorted,
                                              const int* __restrict__ rowp,
                                              const float* __restrict__ xp,
                                              const float* __restrict__ ssrc,
                                              const float* __restrict__ sdst,
                                              const float* __restrict__ ce,
                                              const float* __restrict__ bias,
                                              float* __restrict__ out) {
  constexpr int HO = 64 * V;
  constexpr int OC = HO / H;
  __shared__ float lds_p[4][64][H];
  __shared__ int lds_s[4][64];
  const int wave = threadIdx.x >> 6, lane = threadIdx.x & 63;
  const int n = blockIdx.x * 4 + wave;
  if (n >= NN) return;
  const int rp0 = rowp[n], rp1 = rowp[n + 1];
  const int h_lane = (lane * V) / OC;

  float sd[H], c0[H], c1[H], c2[H];
#pragma unroll
  for (int h = 0; h < H; h++) {
    sd[h] = sdst[n * H + h];
    c0[h] = ce[h];
    c1[h] = ce[H + h];
    c2[h] = ce[2 * H + h];
  }

  // pass 1: max over leaky logits
  float m[H];
#pragma unroll
  for (int h = 0; h < H; h++) m[h] = -1e30f;
  for (int j = rp0 + lane; j < rp1; j += 64) {
    int4 r = sorted[j];
    int s = r.x;
    float e0 = __int_as_float(r.y), e1 = __int_as_float(r.z), e2 = __int_as_float(r.w);
    float sv[H];
    if constexpr (H == 4) {
      float4 v = *(const float4*)(ssrc + 4 * (size_t)s);
      sv[0] = v.x; sv[1] = v.y; sv[2] = v.z; sv[3] = v.w;
    } else if constexpr (H == 2) {
      float2 v = *(const float2*)(ssrc + 2 * (size_t)s);
      sv[0] = v.x; sv[1] = v.y;
    } else {
      sv[0] = ssrc[s];
    }
#pragma unroll
    for (int h = 0; h < H; h++) {
      float a = sv[h] + sd[h] + e0 * c0[h] + e1 * c1[h] + e2 * c2[h];
      a = a > 0.f ? a : 0.2f * a;
      m[h] = fmaxf(m[h], a);
    }
  }
#pragma unroll
  for (int off = 32; off > 0; off >>= 1)
#pragma unroll
    for (int h = 0; h < H; h++) m[h] = fmaxf(m[h], __shfl_xor(m[h], off));

  // pass 2: exp + gather-accumulate
  float den[H];
#pragma unroll
  for (int h = 0; h < H; h++) den[h] = 0.f;
  float acc[V];
#pragma unroll
  for (int i = 0; i < V; i++) acc[i] = 0.f;

  for (int cbase = rp0; cbase < rp1; cbase += 64) {
    const int cnt = min(64, rp1 - cbase);
    if (lane < cnt) {
      int4 r = sorted[cbase + lane];
      int s = r.x;
      float e0 = __int_as_float(r.y), e1 = __int_as_float(r.z), e2 = __int_as_float(r.w);
      float sv[H];
      if constexpr (H == 4) {
        float4 v = *(const float4*)(ssrc + 4 * (size_t)s);
        sv[0] = v.x; sv[1] = v.y; sv[2] = v.z; sv[3] = v.w;
      } else if constexpr (H == 2) {
        float2 v = *(const float2*)(ssrc + 2 * (size_t)s);
        sv[0] = v.x; sv[1] = v.y;
      } else {
        sv[0] = ssrc[s];
      }
#pragma unroll
      for (int h = 0; h < H; h++) {
        float a = sv[h] + sd[h] + e0 * c0[h] + e1 * c1[h] + e2 * c2[h];
        a = a > 0.f ? a : 0.2f * a;
        float p = __expf(a - m[h]);
        den[h] += p;
        lds_p[wave][lane][h] = p;
      }
      lds_s[wave][lane] = s;
    }
    for (int c = 0; c < cnt; c++) {
      const float pw = lds_p[wave][c][h_lane];
      const int s = lds_s[wave][c];
      const float* row = xp + (size_t)s * HO + lane * V;
      if constexpr (V == 4) {
        float4 v = *(const float4*)row;
        acc[0] += pw * v.x; acc[1] += pw * v.y; acc[2] += pw * v.z; acc[3] += pw * v.w;
      } else {
        acc[0] += pw * row[0];
      }
    }
  }
#pragma unroll
  for (int off = 32; off > 0; off >>= 1)
#pragma unroll
    for (int h = 0; h < H; h++) den[h] += __shfl_xor(den[h], off);

  const float dinv = 1.f / den[h_lane];
#pragma unroll
  for (int i = 0; i < V; i++) {
    const int jc = lane * V + i;
    float v = acc[i] * dinv + bias[jc];
    if constexpr (DO_ELU) v = v > 0.f ? v : __expf(v) - 1.f;
    out[(size_t)n * HO + jc] = v;
  }
}

// Layer-3 aggregate: HO=16, H=1 — 16-lane groups, alpha fused.
__global__ __launch_bounds__(256) void k_agg3(const int4* __restrict__ sorted,
                                              const int* __restrict__ rowp,
                                              const float* __restrict__ xp,
                                              const float* __restrict__ ssrc,
                                              const float* __restrict__ sdst,
                                              const float* __restrict__ ce,
                                              const float* __restrict__ bias,
                                              float* __restrict__ out) {
  __shared__ float lds_p[16][16];
  __shared__ int lds_s[16][16];
  int t = threadIdx.x, g = t >> 4, gl = t & 15;
  int n = blockIdx.x * 16 + g;
  if (n >= NN) return;
  int rp0 = rowp[n], rp1 = rowp[n + 1];
  float sd = sdst[n], ce0 = ce[0], ce1 = ce[1], ce2 = ce[2];

  float m = -1e30f;
  for (int j = rp0 + gl; j < rp1; j += 16) {
    int4 r = sorted[j];
    float a = ssrc[r.x] + sd + __int_as_float(r.y) * ce0 +
              __int_as_float(r.z) * ce1 + __int_as_float(r.w) * ce2;
    a = a > 0.f ? a : 0.2f * a;
    m = fmaxf(m, a);
  }
#pragma unroll
  for (int off = 8; off > 0; off >>= 1) m = fmaxf(m, __shfl_xor(m, off));

  float den = 0.f, acc = 0.f;
  for (int cbase = rp0; cbase < rp1; cbase += 16) {
    int cnt = min(16, rp1 - cbase);
    if (gl < cnt) {
      int4 r = sorted[cbase + gl];
      float a = ssrc[r.x] + sd + __int_as_float(r.y) * ce0 +
                __int_as_float(r.z) * ce1 + __int_as_float(r.w) * ce2;
      a = a > 0.f ? a : 0.2f * a;
      float p = __expf(a - m);
      den += p;
      lds_p[g][gl] = p;
      lds_s[g][gl] = r.x;
    }
    for (int c = 0; c < cnt; c++)
      acc += lds_p[g][c] * xp[(size_t)lds_s[g][c] * 16 + gl];
  }
#pragma unroll
  for (int off = 8; off > 0; off >>= 1) den += __shfl_xor(den, off);
  out[(size_t)n * 16 + gl] = acc / den + bias[gl];
}

// ---------------------------------------------------------------- launch

extern "C" void kernel_launch(void* const* d_in, const int* in_sizes, int n_in,
                              void* d_out, int out_size, void* d_ws, size_t ws_size,
                              hipStream_t stream) {
  const float* x   = (const float*)d_in[0];
  const int*   ei  = (const int*)d_in[1];
  const float* ea  = (const float*)d_in[2];
  const float* W1  = (const float*)d_in[3];
  const float* as1 = (const float*)d_in[4];
  const float* ad1 = (const float*)d_in[5];
  const float* We1 = (const float*)d_in[6];
  const float* ae1 = (const float*)d_in[7];
  const float* b1  = (const float*)d_in[8];
  const float* W2  = (const float*)d_in[9];
  const float* as2 = (const float*)d_in[10];
  const float* ad2 = (const float*)d_in[11];
  const float* We2 = (const float*)d_in[12];
  const float* ae2 = (const float*)d_in[13];
  const float* b2  = (const float*)d_in[14];
  const float* W3  = (const float*)d_in[15];
  const float* as3 = (const float*)d_in[16];
  const float* ad3 = (const float*)d_in[17];
  const float* We3 = (const float*)d_in[18];
  const float* ae3 = (const float*)d_in[19];
  const float* b3  = (const float*)d_in[20];
  float* out = (float*)d_out;

  char* base = (char*)d_ws;
  size_t off = 0;
  auto get = [&](size_t bytes) -> char* {
    char* q = base + off;
    off += (bytes + 255) & ~(size_t)255;
    return q;
  };
  int*   cnt    = (int*)get((size_t)NN * 4);
  int*   rowp   = (int*)get((size_t)(NN + 1) * 4);
  int*   cursor = (int*)get((size_t)NN * 4);
  int*   bsum   = (int*)get(256 * 4);
  int4*  sorted = (int4*)get((size_t)NET * 16);
  float* ssrc   = (float*)get((size_t)NN * 16);
  float* sdst   = (float*)get((size_t)NN * 16);
  float* ce     = (float*)get(256);
  float* bufA   = (float*)get((size_t)NN * 256 * 4);
  float* bufB   = (float*)get((size_t)NN * 256 * 4);
  (void)ws_size; (void)in_sizes; (void)n_in; (void)out_size;

  hipMemsetAsync(cnt, 0, (size_t)NN * 4, stream);

  const int EB = (NE + 255) / 256;
  const int SB = (NN + 1023) / 1024;

  k_count<<<EB, 256, 0, stream>>>(ei, cnt);
  k_scan1<<<SB, 256, 0, stream>>>(cnt, bsum);
  k_scan2<<<1, 1, 0, stream>>>(bsum, SB);
  k_scan3<<<SB, 256, 0, stream>>>(cnt, bsum, rowp, cursor);
  k_scatter<<<EB, 256, 0, stream>>>(ei, ea, cursor, sorted);
  k_segloop<<<(NN + 15) / 16, 256, 0, stream>>>(rowp, sorted);

  const int GR = (NN + 127) / 128;  // 391
  const int AGB = (NN + 3) / 4;     // 12500

  // layer 1: 128 -> 4x64
  k_gemm2<<<dim3(GR, 4), 256, 0, stream>>>(x, W1, bufA, NN, 128, 256);
  k_scores<4, 64><<<NN, 256, 0, stream>>>(bufA, as1, ad1, ssrc, sdst);
  k_ce<4, 64><<<1, 64, 0, stream>>>(We1, ae1, ce);
  k_agg2<4, 4, true><<<AGB, 256, 0, stream>>>(sorted, rowp, bufA, ssrc, sdst, ce, b1, bufB);

  // layer 2: 256 -> 2x32
  k_gemm2<<<dim3(GR, 1), 256, 0, stream>>>(bufB, W2, bufA, NN, 256, 64);
  k_scores<2, 32><<<(NN + 3) / 4, 256, 0, stream>>>(bufA, as2, ad2, ssrc, sdst);
  k_ce<2, 32><<<1, 64, 0, stream>>>(We2, ae2, ce);
  k_agg2<2, 1, true><<<AGB, 256, 0, stream>>>(sorted, rowp, bufA, ssrc, sdst, ce, b2, bufB);

  // layer 3: 64 -> 1x16
  k_gemm16<<<(NN + 15) / 16, 256, 0, stream>>>(bufB, W3, bufA);
  k_scores<1, 16><<<(NN + 15) / 16, 256, 0, stream>>>(bufA, as3, ad3, ssrc, sdst);
  k_ce<1, 16><<<1, 64, 0, stream>>>(We3, ae3, ce);
  k_agg3<<<(NN + 15) / 16, 256, 0, stream>>>(sorted, rowp, bufA, ssrc, sdst, ce, b3, out);
}

// Round 9
// 472.220 us; speedup vs baseline: 2.2285x; 1.1377x over previous
//
#include <hip/hip_runtime.h>

// 3-layer GAT with edge attrs on MI355X.
// Round 8: identical to Round 4 (four consecutive GPU acquisition timeouts;
// broker-side capacity failure is independent of kernel content — holding the
// reviewed kernel for clean attribution when a measurement lands).
// (a) bf16 gather payload — GEMMs emit an extra RNE bf16 copy of xp; aggregate
// kernels gather 8B/lane instead of 16B, accumulating fp32. (b) max pass
// removed from aggregates (logits bounded; unstabilized softmax is the same
// ratio) — saves a full sorted[]+ssrc traversal per agg.

constexpr int NN  = 50000;      // nodes
constexpr int NE  = 800000;     // original edges
constexpr int NET = NE + NN;    // edges incl. self loops

static __device__ __forceinline__ unsigned short f2bf(float f) {
  unsigned u = __float_as_uint(f);
  unsigned r = (u + 0x7FFFu + ((u >> 16) & 1u)) >> 16;  // RNE
  return (unsigned short)r;
}
static __device__ __forceinline__ float bf2f(unsigned short b) {
  return __uint_as_float((unsigned)b << 16);
}

// ---------------------------------------------------------------- preprocess

__global__ __launch_bounds__(256) void k_count(const int* __restrict__ ei,
                                               int* __restrict__ cnt) {
  int e = blockIdx.x * 256 + threadIdx.x;
  if (e >= NE) return;
  atomicAdd(&cnt[ei[NE + e]], 1);
}

__global__ __launch_bounds__(256) void k_scan1(const int* __restrict__ cnt,
                                               int* __restrict__ bsum) {
  __shared__ int lds[256];
  int base = blockIdx.x * 1024;
  int s = 0;
  for (int i = 0; i < 4; i++) {
    int idx = base + threadIdx.x * 4 + i;
    if (idx < NN) s += cnt[idx] + 1;
  }
  lds[threadIdx.x] = s;
  __syncthreads();
  for (int off = 128; off > 0; off >>= 1) {
    if (threadIdx.x < off) lds[threadIdx.x] += lds[threadIdx.x + off];
    __syncthreads();
  }
  if (threadIdx.x == 0) bsum[blockIdx.x] = lds[0];
}

__global__ void k_scan2(int* bsum, int nblk) {
  int run = 0;
  for (int i = 0; i < nblk; i++) { int v = bsum[i]; bsum[i] = run; run += v; }
}

__global__ __launch_bounds__(256) void k_scan3(const int* __restrict__ cnt,
                                               const int* __restrict__ bsum,
                                               int* __restrict__ rowp,
                                               int* __restrict__ cursor) {
  __shared__ int lds[256];
  int t = threadIdx.x;
  int base = blockIdx.x * 1024;
  int v[4];
  int s = 0;
  for (int i = 0; i < 4; i++) {
    int idx = base + t * 4 + i;
    v[i] = (idx < NN) ? cnt[idx] + 1 : 0;
    s += v[i];
  }
  lds[t] = s;
  __syncthreads();
  for (int off = 1; off < 256; off <<= 1) {
    int add = (t >= off) ? lds[t - off] : 0;
    __syncthreads();
    lds[t] += add;
    __syncthreads();
  }
  int p = bsum[blockIdx.x] + lds[t] - s;
  for (int i = 0; i < 4; i++) {
    int idx = base + t * 4 + i;
    if (idx < NN) { rowp[idx] = p; cursor[idx] = p; }
    p += v[i];
  }
  if (blockIdx.x == 0 && t == 0) rowp[NN] = NET;
}

__global__ __launch_bounds__(256) void k_scatter(const int* __restrict__ ei,
                                                 const float* __restrict__ ea,
                                                 int* __restrict__ cursor,
                                                 int4* __restrict__ sorted) {
  int e = blockIdx.x * 256 + threadIdx.x;
  if (e >= NE) return;
  int s = ei[e];
  int d = ei[NE + e];
  int pos = atomicAdd(&cursor[d], 1);
  int4 r;
  r.x = s;
  r.y = __float_as_int(ea[3 * (size_t)e + 0]);
  r.z = __float_as_int(ea[3 * (size_t)e + 1]);
  r.w = __float_as_int(ea[3 * (size_t)e + 2]);
  sorted[pos] = r;
}

// Per-node segment sum of edge_attr over real edges -> mean; write self-loop
// record at rowp[n+1]-1. 16-lane group per node, no atomics.
__global__ __launch_bounds__(256) void k_segloop(const int* __restrict__ rowp,
                                                 int4* __restrict__ sorted) {
  int t = threadIdx.x, g = t >> 4, gl = t & 15;
  int n = blockIdx.x * 16 + g;
  if (n >= NN) return;
  int rp0 = rowp[n], rp1e = rowp[n + 1] - 1;
  float s0 = 0.f, s1 = 0.f, s2 = 0.f;
  for (int j = rp0 + gl; j < rp1e; j += 16) {
    int4 r = sorted[j];
    s0 += __int_as_float(r.y);
    s1 += __int_as_float(r.z);
    s2 += __int_as_float(r.w);
  }
#pragma unroll
  for (int off = 8; off > 0; off >>= 1) {
    s0 += __shfl_xor(s0, off);
    s1 += __shfl_xor(s1, off);
    s2 += __shfl_xor(s2, off);
  }
  if (gl == 0) {
    float inv = 1.f / fmaxf((float)(rp1e - rp0), 1.f);
    int4 r;
    r.x = n;
    r.y = __float_as_int(s0 * inv);
    r.z = __float_as_int(s1 * inv);
    r.w = __float_as_int(s2 * inv);
    sorted[rp1e] = r;
  }
}

// ---------------------------------------------------------------- GEMM
// BM=128 BN=64 BK=16, 256 threads, 8x4 per thread. Emits fp32 C + bf16 Cb.
__global__ __launch_bounds__(256) void k_gemm2(const float* __restrict__ A,
                                               const float* __restrict__ W,
                                               float* __restrict__ C,
                                               unsigned short* __restrict__ Cb,
                                               int M, int K, int NC) {
  __shared__ float As[128][17];
  __shared__ float Ws[16][68];
  const int t = threadIdx.x;
  const int tx = t & 15, ty = t >> 4;
  const int row0 = blockIdx.x * 128, col0 = blockIdx.y * 64;
  float acc[8][4] = {};
  const int ar = t >> 2, ac = (t & 3) * 4;
  const int wr = t >> 4, wc = (t & 15) * 4;
  for (int kk = 0; kk < K; kk += 16) {
#pragma unroll
    for (int half = 0; half < 2; half++) {
      int r = ar + half * 64;
      int gr = row0 + r;
      float4 v = make_float4(0.f, 0.f, 0.f, 0.f);
      if (gr < M) v = *(const float4*)(A + (size_t)gr * K + kk + ac);
      As[r][ac] = v.x; As[r][ac + 1] = v.y; As[r][ac + 2] = v.z; As[r][ac + 3] = v.w;
    }
    *(float4*)&Ws[wr][wc] = *(const float4*)(W + (size_t)(kk + wr) * NC + col0 + wc);
    __syncthreads();
#pragma unroll
    for (int k = 0; k < 16; k++) {
      float a[8];
#pragma unroll
      for (int i = 0; i < 8; i++) a[i] = As[ty * 8 + i][k];
      float4 wv = *(const float4*)&Ws[k][tx * 4];
#pragma unroll
      for (int i = 0; i < 8; i++) {
        acc[i][0] += a[i] * wv.x;
        acc[i][1] += a[i] * wv.y;
        acc[i][2] += a[i] * wv.z;
        acc[i][3] += a[i] * wv.w;
      }
    }
    __syncthreads();
  }
#pragma unroll
  for (int i = 0; i < 8; i++) {
    int r = row0 + ty * 8 + i;
    if (r < M) {
      *(float4*)(C + (size_t)r * NC + col0 + tx * 4) = *(float4*)acc[i];
      ushort4 b;
      b.x = f2bf(acc[i][0]); b.y = f2bf(acc[i][1]);
      b.z = f2bf(acc[i][2]); b.w = f2bf(acc[i][3]);
      *(ushort4*)(Cb + (size_t)r * NC + col0 + tx * 4) = b;
    }
  }
}

// NC=16, K=64 special GEMM: 16 nodes per block, LDS-staged. fp32 + bf16 out.
__global__ __launch_bounds__(256) void k_gemm16(const float* __restrict__ A,
                                                const float* __restrict__ W,
                                                float* __restrict__ C,
                                                unsigned short* __restrict__ Cb) {
  __shared__ float hs[16][68];
  __shared__ float Ws[64][16];
  int t = threadIdx.x;
  int n0 = blockIdx.x * 16;
  {
    int r = t >> 2, c = (t & 3) * 4;
    *(float4*)&Ws[r][c] = *(const float4*)(W + r * 16 + c);
  }
  {
    int nl = t >> 4, c = (t & 15) * 4;
    int gn = n0 + nl;
    float4 v = make_float4(0.f, 0.f, 0.f, 0.f);
    if (gn < NN) v = *(const float4*)(A + (size_t)gn * 64 + c);
    *(float4*)&hs[nl][c] = v;
  }
  __syncthreads();
  int nl = t >> 4, col = t & 15;
  float acc = 0.f;
#pragma unroll
  for (int k = 0; k < 64; k++) acc += hs[nl][k] * Ws[k][col];
  int gn = n0 + nl;
  if (gn < NN) {
    C[(size_t)gn * 16 + col] = acc;
    Cb[(size_t)gn * 16 + col] = f2bf(acc);
  }
}

// ---------------------------------------------------------------- scores
template <int H, int O>
__global__ __launch_bounds__(256) void k_scores(const float* __restrict__ xp,
                                                const float* __restrict__ a_src,
                                                const float* __restrict__ a_dst,
                                                float* __restrict__ ssrc,
                                                float* __restrict__ sdst) {
  constexpr int HO = H * O;
  constexpr int NPB = 256 / HO;
  int t = threadIdx.x;
  int j = t % HO;
  int n = blockIdx.x * NPB + t / HO;
  if (n >= NN) return;
  float v = xp[(size_t)n * HO + j];
  float ps = v * a_src[j];
  float pd = v * a_dst[j];
#pragma unroll
  for (int off = O / 2; off > 0; off >>= 1) {
    ps += __shfl_xor(ps, off);
    pd += __shfl_xor(pd, off);
  }
  if ((j & (O - 1)) == 0) {
    int h = j / O;
    ssrc[n * H + h] = ps;
    sdst[n * H + h] = pd;
  }
}

template <int H, int O>
__global__ void k_ce(const float* __restrict__ We, const float* __restrict__ ae,
                     float* __restrict__ c) {
  int t = threadIdx.x;
  if (t >= 3 * H) return;
  int d = t / H, h = t % H;
  float s = 0.f;
  for (int o = 0; o < O; o++) s += We[d * (H * O) + h * O + o] * ae[h * O + o];
  c[t] = s;
}

// ---------------------------------------------------------------- aggregate
// One wave per node, single pass (no max — logits bounded). Per 64-chunk:
// compute p=exp(alpha) lane-parallel -> LDS, then serial bf16-gather-accumulate.
template <int H, int V, bool DO_ELU>
__global__ __launch_bounds__(256) void k_agg2(const int4* __restrict__ sorted,
                                              const int* __restrict__ rowp,
                                              const unsigned short* __restrict__ xpb,
                                              const float* __restrict__ ssrc,
                                              const float* __restrict__ sdst,
                                              const float* __restrict__ ce,
                                              const float* __restrict__ bias,
                                              float* __restrict__ out) {
  constexpr int HO = 64 * V;
  constexpr int OC = HO / H;
  __shared__ float lds_p[4][64][H];
  __shared__ int lds_s[4][64];
  const int wave = threadIdx.x >> 6, lane = threadIdx.x & 63;
  const int n = blockIdx.x * 4 + wave;
  if (n >= NN) return;
  const int rp0 = rowp[n], rp1 = rowp[n + 1];
  const int h_lane = (lane * V) / OC;

  float sd[H], c0[H], c1[H], c2[H];
#pragma unroll
  for (int h = 0; h < H; h++) {
    sd[h] = sdst[n * H + h];
    c0[h] = ce[h];
    c1[h] = ce[H + h];
    c2[h] = ce[2 * H + h];
  }

  float den[H];
#pragma unroll
  for (int h = 0; h < H; h++) den[h] = 0.f;
  float acc[V];
#pragma unroll
  for (int i = 0; i < V; i++) acc[i] = 0.f;

  for (int cbase = rp0; cbase < rp1; cbase += 64) {
    const int cnt = min(64, rp1 - cbase);
    if (lane < cnt) {
      int4 r = sorted[cbase + lane];
      int s = r.x;
      float e0 = __int_as_float(r.y), e1 = __int_as_float(r.z), e2 = __int_as_float(r.w);
      float sv[H];
      if constexpr (H == 4) {
        float4 v = *(const float4*)(ssrc + 4 * (size_t)s);
        sv[0] = v.x; sv[1] = v.y; sv[2] = v.z; sv[3] = v.w;
      } else if constexpr (H == 2) {
        float2 v = *(const float2*)(ssrc + 2 * (size_t)s);
        sv[0] = v.x; sv[1] = v.y;
      } else {
        sv[0] = ssrc[s];
      }
#pragma unroll
      for (int h = 0; h < H; h++) {
        float a = sv[h] + sd[h] + e0 * c0[h] + e1 * c1[h] + e2 * c2[h];
        a = a > 0.f ? a : 0.2f * a;
        float p = __expf(a);
        den[h] += p;
        lds_p[wave][lane][h] = p;
      }
      lds_s[wave][lane] = s;
    }
    for (int c = 0; c < cnt; c++) {
      const float pw = lds_p[wave][c][h_lane];
      const int s = lds_s[wave][c];
      const unsigned short* row = xpb + (size_t)s * HO + lane * V;
      if constexpr (V == 4) {
        ushort4 u = *(const ushort4*)row;
        acc[0] += pw * bf2f(u.x);
        acc[1] += pw * bf2f(u.y);
        acc[2] += pw * bf2f(u.z);
        acc[3] += pw * bf2f(u.w);
      } else {
        acc[0] += pw * bf2f(row[0]);
      }
    }
  }
#pragma unroll
  for (int off = 32; off > 0; off >>= 1)
#pragma unroll
    for (int h = 0; h < H; h++) den[h] += __shfl_xor(den[h], off);

  const float dinv = 1.f / den[h_lane];
#pragma unroll
  for (int i = 0; i < V; i++) {
    const int jc = lane * V + i;
    float v = acc[i] * dinv + bias[jc];
    if constexpr (DO_ELU) v = v > 0.f ? v : __expf(v) - 1.f;
    out[(size_t)n * HO + jc] = v;
  }
}

// Layer-3 aggregate: HO=16, H=1 — 16-lane groups, single-pass, bf16 gather.
__global__ __launch_bounds__(256) void k_agg3(const int4* __restrict__ sorted,
                                              const int* __restrict__ rowp,
                                              const unsigned short* __restrict__ xpb,
                                              const float* __restrict__ ssrc,
                                              const float* __restrict__ sdst,
                                              const float* __restrict__ ce,
                                              const float* __restrict__ bias,
                                              float* __restrict__ out) {
  __shared__ float lds_p[16][16];
  __shared__ int lds_s[16][16];
  int t = threadIdx.x, g = t >> 4, gl = t & 15;
  int n = blockIdx.x * 16 + g;
  if (n >= NN) return;
  int rp0 = rowp[n], rp1 = rowp[n + 1];
  float sd = sdst[n], ce0 = ce[0], ce1 = ce[1], ce2 = ce[2];

  float den = 0.f, acc = 0.f;
  for (int cbase = rp0; cbase < rp1; cbase += 16) {
    int cnt = min(16, rp1 - cbase);
    if (gl < cnt) {
      int4 r = sorted[cbase + gl];
      float a = ssrc[r.x] + sd + __int_as_float(r.y) * ce0 +
                __int_as_float(r.z) * ce1 + __int_as_float(r.w) * ce2;
      a = a > 0.f ? a : 0.2f * a;
      float p = __expf(a);
      den += p;
      lds_p[g][gl] = p;
      lds_s[g][gl] = r.x;
    }
    for (int c = 0; c < cnt; c++)
      acc += lds_p[g][c] * bf2f(xpb[(size_t)lds_s[g][c] * 16 + gl]);
  }
#pragma unroll
  for (int off = 8; off > 0; off >>= 1) den += __shfl_xor(den, off);
  out[(size_t)n * 16 + gl] = acc / den + bias[gl];
}

// ---------------------------------------------------------------- launch

extern "C" void kernel_launch(void* const* d_in, const int* in_sizes, int n_in,
                              void* d_out, int out_size, void* d_ws, size_t ws_size,
                              hipStream_t stream) {
  const float* x   = (const float*)d_in[0];
  const int*   ei  = (const int*)d_in[1];
  const float* ea  = (const float*)d_in[2];
  const float* W1  = (const float*)d_in[3];
  const float* as1 = (const float*)d_in[4];
  const float* ad1 = (const float*)d_in[5];
  const float* We1 = (const float*)d_in[6];
  const float* ae1 = (const float*)d_in[7];
  const float* b1  = (const float*)d_in[8];
  const float* W2  = (const float*)d_in[9];
  const float* as2 = (const float*)d_in[10];
  const float* ad2 = (const float*)d_in[11];
  const float* We2 = (const float*)d_in[12];
  const float* ae2 = (const float*)d_in[13];
  const float* b2  = (const float*)d_in[14];
  const float* W3  = (const float*)d_in[15];
  const float* as3 = (const float*)d_in[16];
  const float* ad3 = (const float*)d_in[17];
  const float* We3 = (const float*)d_in[18];
  const float* ae3 = (const float*)d_in[19];
  const float* b3  = (const float*)d_in[20];
  float* out = (float*)d_out;

  char* base = (char*)d_ws;
  size_t off = 0;
  auto get = [&](size_t bytes) -> char* {
    char* q = base + off;
    off += (bytes + 255) & ~(size_t)255;
    return q;
  };
  int*   cnt    = (int*)get((size_t)NN * 4);
  int*   rowp   = (int*)get((size_t)(NN + 1) * 4);
  int*   cursor = (int*)get((size_t)NN * 4);
  int*   bsum   = (int*)get(256 * 4);
  int4*  sorted = (int4*)get((size_t)NET * 16);
  float* ssrc   = (float*)get((size_t)NN * 16);
  float* sdst   = (float*)get((size_t)NN * 16);
  float* ce     = (float*)get(256);
  float* bufA   = (float*)get((size_t)NN * 256 * 4);
  float* bufB   = (float*)get((size_t)NN * 256 * 4);
  unsigned short* xb = (unsigned short*)get((size_t)NN * 256 * 2);
  (void)ws_size; (void)in_sizes; (void)n_in; (void)out_size;

  hipMemsetAsync(cnt, 0, (size_t)NN * 4, stream);

  const int EB = (NE + 255) / 256;
  const int SB = (NN + 1023) / 1024;

  k_count<<<EB, 256, 0, stream>>>(ei, cnt);
  k_scan1<<<SB, 256, 0, stream>>>(cnt, bsum);
  k_scan2<<<1, 1, 0, stream>>>(bsum, SB);
  k_scan3<<<SB, 256, 0, stream>>>(cnt, bsum, rowp, cursor);
  k_scatter<<<EB, 256, 0, stream>>>(ei, ea, cursor, sorted);
  k_segloop<<<(NN + 15) / 16, 256, 0, stream>>>(rowp, sorted);

  const int GR = (NN + 127) / 128;  // 391
  const int AGB = (NN + 3) / 4;     // 12500

  // layer 1: 128 -> 4x64
  k_gemm2<<<dim3(GR, 4), 256, 0, stream>>>(x, W1, bufA, xb, NN, 128, 256);
  k_scores<4, 64><<<NN, 256, 0, stream>>>(bufA, as1, ad1, ssrc, sdst);
  k_ce<4, 64><<<1, 64, 0, stream>>>(We1, ae1, ce);
  k_agg2<4, 4, true><<<AGB, 256, 0, stream>>>(sorted, rowp, xb, ssrc, sdst, ce, b1, bufB);

  // layer 2: 256 -> 2x32
  k_gemm2<<<dim3(GR, 1), 256, 0, stream>>>(bufB, W2, bufA, xb, NN, 256, 64);
  k_scores<2, 32><<<(NN + 3) / 4, 256, 0, stream>>>(bufA, as2, ad2, ssrc, sdst);
  k_ce<2, 32><<<1, 64, 0, stream>>>(We2, ae2, ce);
  k_agg2<2, 1, true><<<AGB, 256, 0, stream>>>(sorted, rowp, xb, ssrc, sdst, ce, b2, bufB);

  // layer 3: 64 -> 1x16
  k_gemm16<<<(NN + 15) / 16, 256, 0, stream>>>(bufB, W3, bufA, xb);
  k_scores<1, 16><<<(NN + 15) / 16, 256, 0, stream>>>(bufA, as3, ad3, ssrc, sdst);
  k_ce<1, 16><<<1, 64, 0, stream>>>(We3, ae3, ce);
  k_agg3<<<(NN + 15) / 16, 256, 0, stream>>>(sorted, rowp, xb, ssrc, sdst, ce, b3, out);
}

// Round 11
// 427.171 us; speedup vs baseline: 2.4635x; 1.1055x over previous
//
#include <hip/hip_runtime.h>

// 3-layer GAT with edge attrs on MI355X.
// Round 11: identical to Round 10 (acquisition timeout; re-submitting).
// GEMMs on bf16 MFMA (mfma_f32_16x16x32_bf16, fp32 accum): x cast once to
// bf16; W cast during transposed LDS staging; agg epilogues for layers 1/2
// emit bf16 directly (h feeds only the next GEMM) — halves agg writes.
// Aggregates unchanged otherwise (R9 verified: 74us, FETCH halved).

constexpr int NN  = 50000;      // nodes
constexpr int NE  = 800000;     // original edges
constexpr int NET = NE + NN;    // edges incl. self loops

typedef __attribute__((ext_vector_type(8))) short bf16x8;
typedef __attribute__((ext_vector_type(4))) float f32x4;

static __device__ __forceinline__ unsigned short f2bf(float f) {
  unsigned u = __float_as_uint(f);
  unsigned r = (u + 0x7FFFu + ((u >> 16) & 1u)) >> 16;  // RNE
  return (unsigned short)r;
}
static __device__ __forceinline__ float bf2f(unsigned short b) {
  return __uint_as_float((unsigned)b << 16);
}

// ---------------------------------------------------------------- preprocess

__global__ __launch_bounds__(256) void k_count(const int* __restrict__ ei,
                                               int* __restrict__ cnt) {
  int e = blockIdx.x * 256 + threadIdx.x;
  if (e >= NE) return;
  atomicAdd(&cnt[ei[NE + e]], 1);
}

__global__ __launch_bounds__(256) void k_scan1(const int* __restrict__ cnt,
                                               int* __restrict__ bsum) {
  __shared__ int lds[256];
  int base = blockIdx.x * 1024;
  int s = 0;
  for (int i = 0; i < 4; i++) {
    int idx = base + threadIdx.x * 4 + i;
    if (idx < NN) s += cnt[idx] + 1;
  }
  lds[threadIdx.x] = s;
  __syncthreads();
  for (int off = 128; off > 0; off >>= 1) {
    if (threadIdx.x < off) lds[threadIdx.x] += lds[threadIdx.x + off];
    __syncthreads();
  }
  if (threadIdx.x == 0) bsum[blockIdx.x] = lds[0];
}

__global__ void k_scan2(int* bsum, int nblk) {
  int run = 0;
  for (int i = 0; i < nblk; i++) { int v = bsum[i]; bsum[i] = run; run += v; }
}

__global__ __launch_bounds__(256) void k_scan3(const int* __restrict__ cnt,
                                               const int* __restrict__ bsum,
                                               int* __restrict__ rowp,
                                               int* __restrict__ cursor) {
  __shared__ int lds[256];
  int t = threadIdx.x;
  int base = blockIdx.x * 1024;
  int v[4];
  int s = 0;
  for (int i = 0; i < 4; i++) {
    int idx = base + t * 4 + i;
    v[i] = (idx < NN) ? cnt[idx] + 1 : 0;
    s += v[i];
  }
  lds[t] = s;
  __syncthreads();
  for (int off = 1; off < 256; off <<= 1) {
    int add = (t >= off) ? lds[t - off] : 0;
    __syncthreads();
    lds[t] += add;
    __syncthreads();
  }
  int p = bsum[blockIdx.x] + lds[t] - s;
  for (int i = 0; i < 4; i++) {
    int idx = base + t * 4 + i;
    if (idx < NN) { rowp[idx] = p; cursor[idx] = p; }
    p += v[i];
  }
  if (blockIdx.x == 0 && t == 0) rowp[NN] = NET;
}

__global__ __launch_bounds__(256) void k_scatter(const int* __restrict__ ei,
                                                 const float* __restrict__ ea,
                                                 int* __restrict__ cursor,
                                                 int4* __restrict__ sorted) {
  int e = blockIdx.x * 256 + threadIdx.x;
  if (e >= NE) return;
  int s = ei[e];
  int d = ei[NE + e];
  int pos = atomicAdd(&cursor[d], 1);
  int4 r;
  r.x = s;
  r.y = __float_as_int(ea[3 * (size_t)e + 0]);
  r.z = __float_as_int(ea[3 * (size_t)e + 1]);
  r.w = __float_as_int(ea[3 * (size_t)e + 2]);
  sorted[pos] = r;
}

// Per-node segment sum of edge_attr over real edges -> mean; write self-loop
// record at rowp[n+1]-1. 16-lane group per node, no atomics.
__global__ __launch_bounds__(256) void k_segloop(const int* __restrict__ rowp,
                                                 int4* __restrict__ sorted) {
  int t = threadIdx.x, g = t >> 4, gl = t & 15;
  int n = blockIdx.x * 16 + g;
  if (n >= NN) return;
  int rp0 = rowp[n], rp1e = rowp[n + 1] - 1;
  float s0 = 0.f, s1 = 0.f, s2 = 0.f;
  for (int j = rp0 + gl; j < rp1e; j += 16) {
    int4 r = sorted[j];
    s0 += __int_as_float(r.y);
    s1 += __int_as_float(r.z);
    s2 += __int_as_float(r.w);
  }
#pragma unroll
  for (int off = 8; off > 0; off >>= 1) {
    s0 += __shfl_xor(s0, off);
    s1 += __shfl_xor(s1, off);
    s2 += __shfl_xor(s2, off);
  }
  if (gl == 0) {
    float inv = 1.f / fmaxf((float)(rp1e - rp0), 1.f);
    int4 r;
    r.x = n;
    r.y = __float_as_int(s0 * inv);
    r.z = __float_as_int(s1 * inv);
    r.w = __float_as_int(s2 * inv);
    sorted[rp1e] = r;
  }
}

// ---------------------------------------------------------------- cast
__global__ __launch_bounds__(256) void k_cast(const float* __restrict__ in,
                                              unsigned short* __restrict__ out,
                                              int n4) {
  int i = blockIdx.x * 256 + threadIdx.x;
  if (i >= n4) return;
  float4 v = ((const float4*)in)[i];
  ushort4 b;
  b.x = f2bf(v.x); b.y = f2bf(v.y); b.z = f2bf(v.z); b.w = f2bf(v.w);
  ((ushort4*)out)[i] = b;
}

// ---------------------------------------------------------------- MFMA GEMM
// C[M x NC] = A(bf16)[M x K] * W(fp32->bf16)[K x NC]. Block: 256 thr (4 waves),
// tile 64 x BN; wave w owns rows w*16..+16, NT=BN/16 col-tiles, K-step 32.
// Fragment mapping (mfma_f32_16x16x32_bf16): A row=lane&15, k=(lane>>4)*8+j;
// B col=lane&15, same k; D col=lane&15, row=(lane>>4)*4+reg [m89/m91].
// W staged transposed Wt[col][K+8] (pad -> 2-way-free ds_read_b128).
template <int K, int BN>
__global__ __launch_bounds__(256) void k_gemm_mfma(const unsigned short* __restrict__ A,
                                                   const float* __restrict__ W,
                                                   float* __restrict__ C,
                                                   unsigned short* __restrict__ Cb,
                                                   int M, int NC) {
  constexpr int NT = BN / 16;
  constexpr int LGBN = (BN == 64) ? 6 : 4;
  __shared__ unsigned short Wt[BN][K + 8];
  const int t = threadIdx.x;
  const int row0 = blockIdx.x * 64;
  const int col0 = blockIdx.y * BN;
  for (int idx = t; idx < BN * K; idx += 256) {
    int c = idx & (BN - 1);
    int k = idx >> LGBN;
    Wt[c][k] = f2bf(W[(size_t)k * NC + col0 + c]);
  }
  __syncthreads();
  const int wave = t >> 6, lane = t & 63;
  const int rbase = row0 + wave * 16 + (lane & 15);
  const int kgrp = (lane >> 4) * 8;
  const bool rok = rbase < M;
  f32x4 acc[NT];
#pragma unroll
  for (int i = 0; i < NT; i++) acc[i] = f32x4{0.f, 0.f, 0.f, 0.f};
#pragma unroll
  for (int kk = 0; kk < K; kk += 32) {
    bf16x8 a = {};
    if (rok) a = *(const bf16x8*)(A + (size_t)rbase * K + kk + kgrp);
#pragma unroll
    for (int nt = 0; nt < NT; nt++) {
      bf16x8 b = *(const bf16x8*)(&Wt[nt * 16 + (lane & 15)][kk + kgrp]);
      acc[nt] = __builtin_amdgcn_mfma_f32_16x16x32_bf16(a, b, acc[nt], 0, 0, 0);
    }
  }
  const int wr0 = row0 + wave * 16 + (lane >> 4) * 4;
  const int wc = lane & 15;
#pragma unroll
  for (int nt = 0; nt < NT; nt++) {
#pragma unroll
    for (int i = 0; i < 4; i++) {
      int r = wr0 + i;
      if (r < M) {
        float v = acc[nt][i];
        C[(size_t)r * NC + col0 + nt * 16 + wc] = v;
        Cb[(size_t)r * NC + col0 + nt * 16 + wc] = f2bf(v);
      }
    }
  }
}

// ---------------------------------------------------------------- scores
template <int H, int O>
__global__ __launch_bounds__(256) void k_scores(const float* __restrict__ xp,
                                                const float* __restrict__ a_src,
                                                const float* __restrict__ a_dst,
                                                float* __restrict__ ssrc,
                                                float* __restrict__ sdst) {
  constexpr int HO = H * O;
  constexpr int NPB = 256 / HO;
  int t = threadIdx.x;
  int j = t % HO;
  int n = blockIdx.x * NPB + t / HO;
  if (n >= NN) return;
  float v = xp[(size_t)n * HO + j];
  float ps = v * a_src[j];
  float pd = v * a_dst[j];
#pragma unroll
  for (int off = O / 2; off > 0; off >>= 1) {
    ps += __shfl_xor(ps, off);
    pd += __shfl_xor(pd, off);
  }
  if ((j & (O - 1)) == 0) {
    int h = j / O;
    ssrc[n * H + h] = ps;
    sdst[n * H + h] = pd;
  }
}

template <int H, int O>
__global__ void k_ce(const float* __restrict__ We, const float* __restrict__ ae,
                     float* __restrict__ c) {
  int t = threadIdx.x;
  if (t >= 3 * H) return;
  int d = t / H, h = t % H;
  float s = 0.f;
  for (int o = 0; o < O; o++) s += We[d * (H * O) + h * O + o] * ae[h * O + o];
  c[t] = s;
}

// ---------------------------------------------------------------- aggregate
// One wave per node, single pass. Per 64-chunk: p=exp(alpha) lane-parallel ->
// LDS, then serial bf16-gather-accumulate. OB16: write bf16 (h feeds next GEMM).
template <int H, int V, bool DO_ELU, bool OB16>
__global__ __launch_bounds__(256) void k_agg2(const int4* __restrict__ sorted,
                                              const int* __restrict__ rowp,
                                              const unsigned short* __restrict__ xpb,
                                              const float* __restrict__ ssrc,
                                              const float* __restrict__ sdst,
                                              const float* __restrict__ ce,
                                              const float* __restrict__ bias,
                                              void* __restrict__ out) {
  constexpr int HO = 64 * V;
  constexpr int OC = HO / H;
  __shared__ float lds_p[4][64][H];
  __shared__ int lds_s[4][64];
  const int wave = threadIdx.x >> 6, lane = threadIdx.x & 63;
  const int n = blockIdx.x * 4 + wave;
  if (n >= NN) return;
  const int rp0 = rowp[n], rp1 = rowp[n + 1];
  const int h_lane = (lane * V) / OC;

  float sd[H], c0[H], c1[H], c2[H];
#pragma unroll
  for (int h = 0; h < H; h++) {
    sd[h] = sdst[n * H + h];
    c0[h] = ce[h];
    c1[h] = ce[H + h];
    c2[h] = ce[2 * H + h];
  }

  float den[H];
#pragma unroll
  for (int h = 0; h < H; h++) den[h] = 0.f;
  float acc[V];
#pragma unroll
  for (int i = 0; i < V; i++) acc[i] = 0.f;

  for (int cbase = rp0; cbase < rp1; cbase += 64) {
    const int cnt = min(64, rp1 - cbase);
    if (lane < cnt) {
      int4 r = sorted[cbase + lane];
      int s = r.x;
      float e0 = __int_as_float(r.y), e1 = __int_as_float(r.z), e2 = __int_as_float(r.w);
      float sv[H];
      if constexpr (H == 4) {
        float4 v = *(const float4*)(ssrc + 4 * (size_t)s);
        sv[0] = v.x; sv[1] = v.y; sv[2] = v.z; sv[3] = v.w;
      } else if constexpr (H == 2) {
        float2 v = *(const float2*)(ssrc + 2 * (size_t)s);
        sv[0] = v.x; sv[1] = v.y;
      } else {
        sv[0] = ssrc[s];
      }
#pragma unroll
      for (int h = 0; h < H; h++) {
        float a = sv[h] + sd[h] + e0 * c0[h] + e1 * c1[h] + e2 * c2[h];
        a = a > 0.f ? a : 0.2f * a;
        float p = __expf(a);
        den[h] += p;
        lds_p[wave][lane][h] = p;
      }
      lds_s[wave][lane] = s;
    }
    for (int c = 0; c < cnt; c++) {
      const float pw = lds_p[wave][c][h_lane];
      const int s = lds_s[wave][c];
      const unsigned short* row = xpb + (size_t)s * HO + lane * V;
      if constexpr (V == 4) {
        ushort4 u = *(const ushort4*)row;
        acc[0] += pw * bf2f(u.x);
        acc[1] += pw * bf2f(u.y);
        acc[2] += pw * bf2f(u.z);
        acc[3] += pw * bf2f(u.w);
      } else {
        acc[0] += pw * bf2f(row[0]);
      }
    }
  }
#pragma unroll
  for (int off = 32; off > 0; off >>= 1)
#pragma unroll
    for (int h = 0; h < H; h++) den[h] += __shfl_xor(den[h], off);

  const float dinv = 1.f / den[h_lane];
#pragma unroll
  for (int i = 0; i < V; i++) {
    const int jc = lane * V + i;
    float v = acc[i] * dinv + bias[jc];
    if constexpr (DO_ELU) v = v > 0.f ? v : __expf(v) - 1.f;
    if constexpr (OB16) {
      ((unsigned short*)out)[(size_t)n * HO + jc] = f2bf(v);
    } else {
      ((float*)out)[(size_t)n * HO + jc] = v;
    }
  }
}

// Layer-3 aggregate: HO=16, H=1 — 16-lane groups, single-pass, bf16 gather.
__global__ __launch_bounds__(256) void k_agg3(const int4* __restrict__ sorted,
                                              const int* __restrict__ rowp,
                                              const unsigned short* __restrict__ xpb,
                                              const float* __restrict__ ssrc,
                                              const float* __restrict__ sdst,
                                              const float* __restrict__ ce,
                                              const float* __restrict__ bias,
                                              float* __restrict__ out) {
  __shared__ float lds_p[16][16];
  __shared__ int lds_s[16][16];
  int t = threadIdx.x, g = t >> 4, gl = t & 15;
  int n = blockIdx.x * 16 + g;
  if (n >= NN) return;
  int rp0 = rowp[n], rp1 = rowp[n + 1];
  float sd = sdst[n], ce0 = ce[0], ce1 = ce[1], ce2 = ce[2];

  float den = 0.f, acc = 0.f;
  for (int cbase = rp0; cbase < rp1; cbase += 16) {
    int cnt = min(16, rp1 - cbase);
    if (gl < cnt) {
      int4 r = sorted[cbase + gl];
      float a = ssrc[r.x] + sd + __int_as_float(r.y) * ce0 +
                __int_as_float(r.z) * ce1 + __int_as_float(r.w) * ce2;
      a = a > 0.f ? a : 0.2f * a;
      float p = __expf(a);
      den += p;
      lds_p[g][gl] = p;
      lds_s[g][gl] = r.x;
    }
    for (int c = 0; c < cnt; c++)
      acc += lds_p[g][c] * bf2f(xpb[(size_t)lds_s[g][c] * 16 + gl]);
  }
#pragma unroll
  for (int off = 8; off > 0; off >>= 1) den += __shfl_xor(den, off);
  out[(size_t)n * 16 + gl] = acc / den + bias[gl];
}

// ---------------------------------------------------------------- launch

extern "C" void kernel_launch(void* const* d_in, const int* in_sizes, int n_in,
                              void* d_out, int out_size, void* d_ws, size_t ws_size,
                              hipStream_t stream) {
  const float* x   = (const float*)d_in[0];
  const int*   ei  = (const int*)d_in[1];
  const float* ea  = (const float*)d_in[2];
  const float* W1  = (const float*)d_in[3];
  const float* as1 = (const float*)d_in[4];
  const float* ad1 = (const float*)d_in[5];
  const float* We1 = (const float*)d_in[6];
  const float* ae1 = (const float*)d_in[7];
  const float* b1  = (const float*)d_in[8];
  const float* W2  = (const float*)d_in[9];
  const float* as2 = (const float*)d_in[10];
  const float* ad2 = (const float*)d_in[11];
  const float* We2 = (const float*)d_in[12];
  const float* ae2 = (const float*)d_in[13];
  const float* b2  = (const float*)d_in[14];
  const float* W3  = (const float*)d_in[15];
  const float* as3 = (const float*)d_in[16];
  const float* ad3 = (const float*)d_in[17];
  const float* We3 = (const float*)d_in[18];
  const float* ae3 = (const float*)d_in[19];
  const float* b3  = (const float*)d_in[20];
  float* out = (float*)d_out;

  char* base = (char*)d_ws;
  size_t off = 0;
  auto get = [&](size_t bytes) -> char* {
    char* q = base + off;
    off += (bytes + 255) & ~(size_t)255;
    return q;
  };
  int*   cnt    = (int*)get((size_t)NN * 4);
  int*   rowp   = (int*)get((size_t)(NN + 1) * 4);
  int*   cursor = (int*)get((size_t)NN * 4);
  int*   bsum   = (int*)get(256 * 4);
  int4*  sorted = (int4*)get((size_t)NET * 16);
  float* ssrc   = (float*)get((size_t)NN * 16);
  float* sdst   = (float*)get((size_t)NN * 16);
  float* ce     = (float*)get(256);
  float* bufA   = (float*)get((size_t)NN * 256 * 4);        // fp32 xp (scores)
  unsigned short* xb  = (unsigned short*)get((size_t)NN * 256 * 2);  // bf16 xp (gather)
  unsigned short* x16 = (unsigned short*)get((size_t)NN * 128 * 2);  // bf16 x
  unsigned short* h1b = (unsigned short*)get((size_t)NN * 256 * 2);  // bf16 h1
  unsigned short* h2b = (unsigned short*)get((size_t)NN * 64 * 2);   // bf16 h2
  (void)ws_size; (void)in_sizes; (void)n_in; (void)out_size;

  hipMemsetAsync(cnt, 0, (size_t)NN * 4, stream);

  const int EB = (NE + 255) / 256;
  const int SB = (NN + 1023) / 1024;

  k_count<<<EB, 256, 0, stream>>>(ei, cnt);
  k_scan1<<<SB, 256, 0, stream>>>(cnt, bsum);
  k_scan2<<<1, 1, 0, stream>>>(bsum, SB);
  k_scan3<<<SB, 256, 0, stream>>>(cnt, bsum, rowp, cursor);
  k_scatter<<<EB, 256, 0, stream>>>(ei, ea, cursor, sorted);
  k_segloop<<<(NN + 15) / 16, 256, 0, stream>>>(rowp, sorted);

  const int GR64 = (NN + 63) / 64;  // 782
  const int AGB = (NN + 3) / 4;     // 12500

  k_cast<<<(NN * 128 / 4 + 255) / 256, 256, 0, stream>>>(x, x16, NN * 128 / 4);

  // layer 1: 128 -> 4x64 (MFMA)
  k_gemm_mfma<128, 64><<<dim3(GR64, 4), 256, 0, stream>>>(x16, W1, bufA, xb, NN, 256);
  k_scores<4, 64><<<NN, 256, 0, stream>>>(bufA, as1, ad1, ssrc, sdst);
  k_ce<4, 64><<<1, 64, 0, stream>>>(We1, ae1, ce);
  k_agg2<4, 4, true, true><<<AGB, 256, 0, stream>>>(sorted, rowp, xb, ssrc, sdst, ce, b1, (void*)h1b);

  // layer 2: 256 -> 2x32 (MFMA)
  k_gemm_mfma<256, 64><<<dim3(GR64, 1), 256, 0, stream>>>(h1b, W2, bufA, xb, NN, 64);
  k_scores<2, 32><<<(NN + 3) / 4, 256, 0, stream>>>(bufA, as2, ad2, ssrc, sdst);
  k_ce<2, 32><<<1, 64, 0, stream>>>(We2, ae2, ce);
  k_agg2<2, 1, true, true><<<AGB, 256, 0, stream>>>(sorted, rowp, xb, ssrc, sdst, ce, b2, (void*)h2b);

  // layer 3: 64 -> 1x16 (MFMA)
  k_gemm_mfma<64, 16><<<dim3(GR64, 1), 256, 0, stream>>>(h2b, W3, bufA, xb, NN, 16);
  k_scores<1, 16><<<(NN + 15) / 16, 256, 0, stream>>>(bufA, as3, ad3, ssrc, sdst);
  k_ce<1, 16><<<1, 64, 0, stream>>>(We3, ae3, ce);
  k_agg3<<<(NN + 15) / 16, 256, 0, stream>>>(sorted, rowp, xb, ssrc, sdst, ce, b3, out);
}

// Round 12
// 392.186 us; speedup vs baseline: 2.6832x; 1.0892x over previous
//
#include <hip/hip_runtime.h>

// 3-layer GAT with edge attrs on MI355X.
// Round 12: scores fused into GEMM epilogue (shfl-reduce of fp32 acc ->
// ssrc/sdst; head boundary aligns with 16-col tiles in all layers) — kills
// k_scores x3 and the fp32 xp buffer entirely (GEMMs emit bf16 only).
// GEMM1 converts fp32 x in-register (kills k_cast). Single k_ce_all launch.
// Aggregates unchanged (R11-verified: agg1 at its gather-traffic floor).

constexpr int NN  = 50000;      // nodes
constexpr int NE  = 800000;     // original edges
constexpr int NET = NE + NN;    // edges incl. self loops

typedef __attribute__((ext_vector_type(8))) short bf16x8;
typedef __attribute__((ext_vector_type(4))) float f32x4;

static __device__ __forceinline__ unsigned short f2bf(float f) {
  unsigned u = __float_as_uint(f);
  unsigned r = (u + 0x7FFFu + ((u >> 16) & 1u)) >> 16;  // RNE
  return (unsigned short)r;
}
static __device__ __forceinline__ float bf2f(unsigned short b) {
  return __uint_as_float((unsigned)b << 16);
}

// ---------------------------------------------------------------- preprocess

__global__ __launch_bounds__(256) void k_count(const int* __restrict__ ei,
                                               int* __restrict__ cnt) {
  int e = blockIdx.x * 256 + threadIdx.x;
  if (e >= NE) return;
  atomicAdd(&cnt[ei[NE + e]], 1);
}

__global__ __launch_bounds__(256) void k_scan1(const int* __restrict__ cnt,
                                               int* __restrict__ bsum) {
  __shared__ int lds[256];
  int base = blockIdx.x * 1024;
  int s = 0;
  for (int i = 0; i < 4; i++) {
    int idx = base + threadIdx.x * 4 + i;
    if (idx < NN) s += cnt[idx] + 1;
  }
  lds[threadIdx.x] = s;
  __syncthreads();
  for (int off = 128; off > 0; off >>= 1) {
    if (threadIdx.x < off) lds[threadIdx.x] += lds[threadIdx.x + off];
    __syncthreads();
  }
  if (threadIdx.x == 0) bsum[blockIdx.x] = lds[0];
}

__global__ void k_scan2(int* bsum, int nblk) {
  int run = 0;
  for (int i = 0; i < nblk; i++) { int v = bsum[i]; bsum[i] = run; run += v; }
}

__global__ __launch_bounds__(256) void k_scan3(const int* __restrict__ cnt,
                                               const int* __restrict__ bsum,
                                               int* __restrict__ rowp,
                                               int* __restrict__ cursor) {
  __shared__ int lds[256];
  int t = threadIdx.x;
  int base = blockIdx.x * 1024;
  int v[4];
  int s = 0;
  for (int i = 0; i < 4; i++) {
    int idx = base + t * 4 + i;
    v[i] = (idx < NN) ? cnt[idx] + 1 : 0;
    s += v[i];
  }
  lds[t] = s;
  __syncthreads();
  for (int off = 1; off < 256; off <<= 1) {
    int add = (t >= off) ? lds[t - off] : 0;
    __syncthreads();
    lds[t] += add;
    __syncthreads();
  }
  int p = bsum[blockIdx.x] + lds[t] - s;
  for (int i = 0; i < 4; i++) {
    int idx = base + t * 4 + i;
    if (idx < NN) { rowp[idx] = p; cursor[idx] = p; }
    p += v[i];
  }
  if (blockIdx.x == 0 && t == 0) rowp[NN] = NET;
}

__global__ __launch_bounds__(256) void k_scatter(const int* __restrict__ ei,
                                                 const float* __restrict__ ea,
                                                 int* __restrict__ cursor,
                                                 int4* __restrict__ sorted) {
  int e = blockIdx.x * 256 + threadIdx.x;
  if (e >= NE) return;
  int s = ei[e];
  int d = ei[NE + e];
  int pos = atomicAdd(&cursor[d], 1);
  int4 r;
  r.x = s;
  r.y = __float_as_int(ea[3 * (size_t)e + 0]);
  r.z = __float_as_int(ea[3 * (size_t)e + 1]);
  r.w = __float_as_int(ea[3 * (size_t)e + 2]);
  sorted[pos] = r;
}

// Per-node segment sum of edge_attr over real edges -> mean; write self-loop
// record at rowp[n+1]-1. 16-lane group per node, no atomics.
__global__ __launch_bounds__(256) void k_segloop(const int* __restrict__ rowp,
                                                 int4* __restrict__ sorted) {
  int t = threadIdx.x, g = t >> 4, gl = t & 15;
  int n = blockIdx.x * 16 + g;
  if (n >= NN) return;
  int rp0 = rowp[n], rp1e = rowp[n + 1] - 1;
  float s0 = 0.f, s1 = 0.f, s2 = 0.f;
  for (int j = rp0 + gl; j < rp1e; j += 16) {
    int4 r = sorted[j];
    s0 += __int_as_float(r.y);
    s1 += __int_as_float(r.z);
    s2 += __int_as_float(r.w);
  }
#pragma unroll
  for (int off = 8; off > 0; off >>= 1) {
    s0 += __shfl_xor(s0, off);
    s1 += __shfl_xor(s1, off);
    s2 += __shfl_xor(s2, off);
  }
  if (gl == 0) {
    float inv = 1.f / fmaxf((float)(rp1e - rp0), 1.f);
    int4 r;
    r.x = n;
    r.y = __float_as_int(s0 * inv);
    r.z = __float_as_int(s1 * inv);
    r.w = __float_as_int(s2 * inv);
    sorted[rp1e] = r;
  }
}

// ---------------------------------------------------------------- edge coeffs
// ce layout: [0..11]=L1 (d*4+h), [16..21]=L2 (d*2+h), [24..26]=L3 (d).
__global__ void k_ce_all(const float* __restrict__ We1, const float* __restrict__ ae1,
                         const float* __restrict__ We2, const float* __restrict__ ae2,
                         const float* __restrict__ We3, const float* __restrict__ ae3,
                         float* __restrict__ ce) {
  int t = threadIdx.x;
  if (t < 12) {
    int d = t / 4, h = t % 4;
    float s = 0.f;
    for (int o = 0; o < 64; o++) s += We1[d * 256 + h * 64 + o] * ae1[h * 64 + o];
    ce[t] = s;
  } else if (t >= 16 && t < 22) {
    int u = t - 16, d = u / 2, h = u % 2;
    float s = 0.f;
    for (int o = 0; o < 32; o++) s += We2[d * 64 + h * 32 + o] * ae2[h * 32 + o];
    ce[t] = s;
  } else if (t >= 24 && t < 27) {
    int d = t - 24;
    float s = 0.f;
    for (int o = 0; o < 16; o++) s += We3[d * 16 + o] * ae3[o];
    ce[t] = s;
  }
}

// ---------------------------------------------------------------- MFMA GEMM + fused scores
// Cb(bf16)[M x NC] = A[M x K] * W(fp32->bf16)[K x NC]; epilogue computes
// ssrc/sdst from the fp32 acc: per row-group 16-lane shfl reduce; each 16-col
// tile lies in exactly one head (O in {64,32,16} divides tile offsets).
// Fragment mapping (mfma_f32_16x16x32_bf16): A row=lane&15, k=(lane>>4)*8+j;
// B col=lane&15, same k; D col=lane&15, row=(lane>>4)*4+reg [m89/m91].
template <int K, int BN, int O, bool AFP32>
__global__ __launch_bounds__(256) void k_gemm_sc(const void* __restrict__ Ap,
                                                 const float* __restrict__ W,
                                                 unsigned short* __restrict__ Cb,
                                                 const float* __restrict__ a_src,
                                                 const float* __restrict__ a_dst,
                                                 float* __restrict__ ssrc,
                                                 float* __restrict__ sdst,
                                                 int M, int NC) {
  constexpr int NT = BN / 16;
  constexpr int HL = BN / O;  // heads local to this block
  __shared__ unsigned short Wt[BN][K + 8];
  const int t = threadIdx.x;
  const int row0 = blockIdx.x * 64;
  const int col0 = blockIdx.y * BN;
  const int H = NC / O;
  for (int idx = t; idx < BN * K; idx += 256) {
    int c = idx % BN;
    int k = idx / BN;
    Wt[c][k] = f2bf(W[(size_t)k * NC + col0 + c]);
  }
  __syncthreads();
  const int wave = t >> 6, lane = t & 63;
  const int wc = lane & 15;
  const int rbase = row0 + wave * 16 + wc;
  const int kgrp = (lane >> 4) * 8;
  const bool rok = rbase < M;
  f32x4 acc[NT];
#pragma unroll
  for (int i = 0; i < NT; i++) acc[i] = f32x4{0.f, 0.f, 0.f, 0.f};
#pragma unroll
  for (int kk = 0; kk < K; kk += 32) {
    bf16x8 a = {};
    if (rok) {
      if constexpr (AFP32) {
        const float* Af = (const float*)Ap;
        float4 v0 = *(const float4*)(Af + (size_t)rbase * K + kk + kgrp);
        float4 v1 = *(const float4*)(Af + (size_t)rbase * K + kk + kgrp + 4);
        a[0] = (short)f2bf(v0.x); a[1] = (short)f2bf(v0.y);
        a[2] = (short)f2bf(v0.z); a[3] = (short)f2bf(v0.w);
        a[4] = (short)f2bf(v1.x); a[5] = (short)f2bf(v1.y);
        a[6] = (short)f2bf(v1.z); a[7] = (short)f2bf(v1.w);
      } else {
        a = *(const bf16x8*)((const unsigned short*)Ap + (size_t)rbase * K + kk + kgrp);
      }
    }
#pragma unroll
    for (int nt = 0; nt < NT; nt++) {
      bf16x8 b = *(const bf16x8*)(&Wt[nt * 16 + wc][kk + kgrp]);
      acc[nt] = __builtin_amdgcn_mfma_f32_16x16x32_bf16(a, b, acc[nt], 0, 0, 0);
    }
  }
  const int wr0 = row0 + wave * 16 + (lane >> 4) * 4;
  float psrc[4][HL], pdst[4][HL];
#pragma unroll
  for (int i = 0; i < 4; i++)
#pragma unroll
    for (int hl = 0; hl < HL; hl++) { psrc[i][hl] = 0.f; pdst[i][hl] = 0.f; }
#pragma unroll
  for (int nt = 0; nt < NT; nt++) {
    const int col = col0 + nt * 16 + wc;
    const float asv = a_src[col];
    const float adv = a_dst[col];
    constexpr int dummy = 0; (void)dummy;
    const int hl = (nt * 16) / O;
#pragma unroll
    for (int i = 0; i < 4; i++) {
      int r = wr0 + i;
      float v = acc[nt][i];
      if (r < M) Cb[(size_t)r * NC + col] = f2bf(v);
      psrc[i][hl] += v * asv;
      pdst[i][hl] += v * adv;
    }
  }
#pragma unroll
  for (int off = 1; off < 16; off <<= 1)
#pragma unroll
    for (int i = 0; i < 4; i++)
#pragma unroll
      for (int hl = 0; hl < HL; hl++) {
        psrc[i][hl] += __shfl_xor(psrc[i][hl], off);
        pdst[i][hl] += __shfl_xor(pdst[i][hl], off);
      }
  if (wc == 0) {
#pragma unroll
    for (int i = 0; i < 4; i++) {
      int r = wr0 + i;
      if (r < M) {
#pragma unroll
        for (int hl = 0; hl < HL; hl++) {
          int h = col0 / O + hl;
          ssrc[r * H + h] = psrc[i][hl];
          sdst[r * H + h] = pdst[i][hl];
        }
      }
    }
  }
}

// ---------------------------------------------------------------- aggregate
// One wave per node, single pass. Per 64-chunk: p=exp(alpha) lane-parallel ->
// LDS, then serial bf16-gather-accumulate. OB16: write bf16 (h feeds next GEMM).
template <int H, int V, bool DO_ELU, bool OB16>
__global__ __launch_bounds__(256) void k_agg2(const int4* __restrict__ sorted,
                                              const int* __restrict__ rowp,
                                              const unsigned short* __restrict__ xpb,
                                              const float* __restrict__ ssrc,
                                              const float* __restrict__ sdst,
                                              const float* __restrict__ ce,
                                              const float* __restrict__ bias,
                                              void* __restrict__ out) {
  constexpr int HO = 64 * V;
  constexpr int OC = HO / H;
  __shared__ float lds_p[4][64][H];
  __shared__ int lds_s[4][64];
  const int wave = threadIdx.x >> 6, lane = threadIdx.x & 63;
  const int n = blockIdx.x * 4 + wave;
  if (n >= NN) return;
  const int rp0 = rowp[n], rp1 = rowp[n + 1];
  const int h_lane = (lane * V) / OC;

  float sd[H], c0[H], c1[H], c2[H];
#pragma unroll
  for (int h = 0; h < H; h++) {
    sd[h] = sdst[n * H + h];
    c0[h] = ce[h];
    c1[h] = ce[H + h];
    c2[h] = ce[2 * H + h];
  }

  float den[H];
#pragma unroll
  for (int h = 0; h < H; h++) den[h] = 0.f;
  float acc[V];
#pragma unroll
  for (int i = 0; i < V; i++) acc[i] = 0.f;

  for (int cbase = rp0; cbase < rp1; cbase += 64) {
    const int cnt = min(64, rp1 - cbase);
    if (lane < cnt) {
      int4 r = sorted[cbase + lane];
      int s = r.x;
      float e0 = __int_as_float(r.y), e1 = __int_as_float(r.z), e2 = __int_as_float(r.w);
      float sv[H];
      if constexpr (H == 4) {
        float4 v = *(const float4*)(ssrc + 4 * (size_t)s);
        sv[0] = v.x; sv[1] = v.y; sv[2] = v.z; sv[3] = v.w;
      } else if constexpr (H == 2) {
        float2 v = *(const float2*)(ssrc + 2 * (size_t)s);
        sv[0] = v.x; sv[1] = v.y;
      } else {
        sv[0] = ssrc[s];
      }
#pragma unroll
      for (int h = 0; h < H; h++) {
        float a = sv[h] + sd[h] + e0 * c0[h] + e1 * c1[h] + e2 * c2[h];
        a = a > 0.f ? a : 0.2f * a;
        float p = __expf(a);
        den[h] += p;
        lds_p[wave][lane][h] = p;
      }
      lds_s[wave][lane] = s;
    }
    for (int c = 0; c < cnt; c++) {
      const float pw = lds_p[wave][c][h_lane];
      const int s = lds_s[wave][c];
      const unsigned short* row = xpb + (size_t)s * HO + lane * V;
      if constexpr (V == 4) {
        ushort4 u = *(const ushort4*)row;
        acc[0] += pw * bf2f(u.x);
        acc[1] += pw * bf2f(u.y);
        acc[2] += pw * bf2f(u.z);
        acc[3] += pw * bf2f(u.w);
      } else {
        acc[0] += pw * bf2f(row[0]);
      }
    }
  }
#pragma unroll
  for (int off = 32; off > 0; off >>= 1)
#pragma unroll
    for (int h = 0; h < H; h++) den[h] += __shfl_xor(den[h], off);

  const float dinv = 1.f / den[h_lane];
#pragma unroll
  for (int i = 0; i < V; i++) {
    const int jc = lane * V + i;
    float v = acc[i] * dinv + bias[jc];
    if constexpr (DO_ELU) v = v > 0.f ? v : __expf(v) - 1.f;
    if constexpr (OB16) {
      ((unsigned short*)out)[(size_t)n * HO + jc] = f2bf(v);
    } else {
      ((float*)out)[(size_t)n * HO + jc] = v;
    }
  }
}

// Layer-3 aggregate: HO=16, H=1 — 16-lane groups, single-pass, bf16 gather.
__global__ __launch_bounds__(256) void k_agg3(const int4* __restrict__ sorted,
                                              const int* __restrict__ rowp,
                                              const unsigned short* __restrict__ xpb,
                                              const float* __restrict__ ssrc,
                                              const float* __restrict__ sdst,
                                              const float* __restrict__ ce,
                                              const float* __restrict__ bias,
                                              float* __restrict__ out) {
  __shared__ float lds_p[16][16];
  __shared__ int lds_s[16][16];
  int t = threadIdx.x, g = t >> 4, gl = t & 15;
  int n = blockIdx.x * 16 + g;
  if (n >= NN) return;
  int rp0 = rowp[n], rp1 = rowp[n + 1];
  float sd = sdst[n], ce0 = ce[0], ce1 = ce[1], ce2 = ce[2];

  float den = 0.f, acc = 0.f;
  for (int cbase = rp0; cbase < rp1; cbase += 16) {
    int cnt = min(16, rp1 - cbase);
    if (gl < cnt) {
      int4 r = sorted[cbase + gl];
      float a = ssrc[r.x] + sd + __int_as_float(r.y) * ce0 +
                __int_as_float(r.z) * ce1 + __int_as_float(r.w) * ce2;
      a = a > 0.f ? a : 0.2f * a;
      float p = __expf(a);
      den += p;
      lds_p[g][gl] = p;
      lds_s[g][gl] = r.x;
    }
    for (int c = 0; c < cnt; c++)
      acc += lds_p[g][c] * bf2f(xpb[(size_t)lds_s[g][c] * 16 + gl]);
  }
#pragma unroll
  for (int off = 8; off > 0; off >>= 1) den += __shfl_xor(den, off);
  out[(size_t)n * 16 + gl] = acc / den + bias[gl];
}

// ---------------------------------------------------------------- launch

extern "C" void kernel_launch(void* const* d_in, const int* in_sizes, int n_in,
                              void* d_out, int out_size, void* d_ws, size_t ws_size,
                              hipStream_t stream) {
  const float* x   = (const float*)d_in[0];
  const int*   ei  = (const int*)d_in[1];
  const float* ea  = (const float*)d_in[2];
  const float* W1  = (const float*)d_in[3];
  const float* as1 = (const float*)d_in[4];
  const float* ad1 = (const float*)d_in[5];
  const float* We1 = (const float*)d_in[6];
  const float* ae1 = (const float*)d_in[7];
  const float* b1  = (const float*)d_in[8];
  const float* W2  = (const float*)d_in[9];
  const float* as2 = (const float*)d_in[10];
  const float* ad2 = (const float*)d_in[11];
  const float* We2 = (const float*)d_in[12];
  const float* ae2 = (const float*)d_in[13];
  const float* b2  = (const float*)d_in[14];
  const float* W3  = (const float*)d_in[15];
  const float* as3 = (const float*)d_in[16];
  const float* ad3 = (const float*)d_in[17];
  const float* We3 = (const float*)d_in[18];
  const float* ae3 = (const float*)d_in[19];
  const float* b3  = (const float*)d_in[20];
  float* out = (float*)d_out;

  char* base = (char*)d_ws;
  size_t off = 0;
  auto get = [&](size_t bytes) -> char* {
    char* q = base + off;
    off += (bytes + 255) & ~(size_t)255;
    return q;
  };
  int*   cnt    = (int*)get((size_t)NN * 4);
  int*   rowp   = (int*)get((size_t)(NN + 1) * 4);
  int*   cursor = (int*)get((size_t)NN * 4);
  int*   bsum   = (int*)get(256 * 4);
  int4*  sorted = (int4*)get((size_t)NET * 16);
  float* ssrc   = (float*)get((size_t)NN * 16);
  float* sdst   = (float*)get((size_t)NN * 16);
  float* ce     = (float*)get(256);
  unsigned short* xb  = (unsigned short*)get((size_t)NN * 256 * 2);  // bf16 xp (gather)
  unsigned short* h1b = (unsigned short*)get((size_t)NN * 256 * 2);  // bf16 h1
  unsigned short* h2b = (unsigned short*)get((size_t)NN * 64 * 2);   // bf16 h2
  (void)ws_size; (void)in_sizes; (void)n_in; (void)out_size;

  hipMemsetAsync(cnt, 0, (size_t)NN * 4, stream);

  const int EB = (NE + 255) / 256;
  const int SB = (NN + 1023) / 1024;

  k_count<<<EB, 256, 0, stream>>>(ei, cnt);
  k_scan1<<<SB, 256, 0, stream>>>(cnt, bsum);
  k_scan2<<<1, 1, 0, stream>>>(bsum, SB);
  k_scan3<<<SB, 256, 0, stream>>>(cnt, bsum, rowp, cursor);
  k_scatter<<<EB, 256, 0, stream>>>(ei, ea, cursor, sorted);
  k_segloop<<<(NN + 15) / 16, 256, 0, stream>>>(rowp, sorted);
  k_ce_all<<<1, 64, 0, stream>>>(We1, ae1, We2, ae2, We3, ae3, ce);

  const int GR64 = (NN + 63) / 64;  // 782
  const int AGB = (NN + 3) / 4;     // 12500

  // layer 1: 128 -> 4x64 (MFMA + fused scores; A = fp32 x)
  k_gemm_sc<128, 64, 64, true><<<dim3(GR64, 4), 256, 0, stream>>>(
      (const void*)x, W1, xb, as1, ad1, ssrc, sdst, NN, 256);
  k_agg2<4, 4, true, true><<<AGB, 256, 0, stream>>>(sorted, rowp, xb, ssrc, sdst, ce, b1, (void*)h1b);

  // layer 2: 256 -> 2x32 (MFMA + fused scores; A = bf16 h1)
  k_gemm_sc<256, 64, 32, false><<<dim3(GR64, 1), 256, 0, stream>>>(
      (const void*)h1b, W2, xb, as2, ad2, ssrc, sdst, NN, 64);
  k_agg2<2, 1, true, true><<<AGB, 256, 0, stream>>>(sorted, rowp, xb, ssrc, sdst, ce + 16, b2, (void*)h2b);

  // layer 3: 64 -> 1x16 (MFMA + fused scores; A = bf16 h2)
  k_gemm_sc<64, 16, 16, false><<<dim3(GR64, 1), 256, 0, stream>>>(
      (const void*)h2b, W3, xb, as3, ad3, ssrc, sdst, NN, 16);
  k_agg3<<<(NN + 15) / 16, 256, 0, stream>>>(sorted, rowp, xb, ssrc, sdst, ce + 24, b3, out);
}

// Round 16
// 355.093 us; speedup vs baseline: 2.9635x; 1.1045x over previous
//
#include <hip/hip_runtime.h>

// 3-layer GAT with edge attrs on MI355X.
// Round 16: identical to Round 13 (three consecutive acquisition timeouts;
// re-submitting unchanged for clean attribution when a measurement lands).
// (a) CSR build re-atomized: k_rank (one atomic/edge, return value doubles as
// within-segment rank) + k_place (scatter, NO atomics) replaces count+scatter's
// 1.6M atomics with 800k. (b) layer-2 aggregate processes 2 edges/iter
// (ushort2/lane, half-wave split, shfl(32) combine) — halves the serial
// gather-loop trips. (c) ce folded into scan2. agg1/GEMMs unchanged
// (R12-verified; agg1 at its ~6.5 TB/s logical gather floor).

constexpr int NN  = 50000;      // nodes
constexpr int NE  = 800000;     // original edges
constexpr int NET = NE + NN;    // edges incl. self loops

typedef __attribute__((ext_vector_type(8))) short bf16x8;
typedef __attribute__((ext_vector_type(4))) float f32x4;

static __device__ __forceinline__ unsigned short f2bf(float f) {
  unsigned u = __float_as_uint(f);
  unsigned r = (u + 0x7FFFu + ((u >> 16) & 1u)) >> 16;  // RNE
  return (unsigned short)r;
}
static __device__ __forceinline__ float bf2f(unsigned short b) {
  return __uint_as_float((unsigned)b << 16);
}

// ---------------------------------------------------------------- preprocess

// One atomic per edge; returned old value = rank of edge within its dst segment.
__global__ __launch_bounds__(256) void k_rank(const int* __restrict__ ei,
                                              int* __restrict__ deg,
                                              int* __restrict__ rank) {
  int e = blockIdx.x * 256 + threadIdx.x;
  if (e >= NE) return;
  rank[e] = atomicAdd(&deg[ei[NE + e]], 1);
}

__global__ __launch_bounds__(256) void k_scan1(const int* __restrict__ deg,
                                               int* __restrict__ bsum) {
  __shared__ int lds[256];
  int base = blockIdx.x * 1024;
  int s = 0;
  for (int i = 0; i < 4; i++) {
    int idx = base + threadIdx.x * 4 + i;
    if (idx < NN) s += deg[idx] + 1;
  }
  lds[threadIdx.x] = s;
  __syncthreads();
  for (int off = 128; off > 0; off >>= 1) {
    if (threadIdx.x < off) lds[threadIdx.x] += lds[threadIdx.x + off];
    __syncthreads();
  }
  if (threadIdx.x == 0) bsum[blockIdx.x] = lds[0];
}

// thread 63: serial block-sum scan; threads 0..26: edge-coeff folds.
// ce layout: [0..11]=L1 (d*4+h), [16..21]=L2 (d*2+h), [24..26]=L3 (d).
__global__ void k_scan2_ce(int* __restrict__ bsum, int nblk,
                           const float* __restrict__ We1, const float* __restrict__ ae1,
                           const float* __restrict__ We2, const float* __restrict__ ae2,
                           const float* __restrict__ We3, const float* __restrict__ ae3,
                           float* __restrict__ ce) {
  int t = threadIdx.x;
  if (t == 63) {
    int run = 0;
    for (int i = 0; i < nblk; i++) { int v = bsum[i]; bsum[i] = run; run += v; }
  } else if (t < 12) {
    int d = t / 4, h = t % 4;
    float s = 0.f;
    for (int o = 0; o < 64; o++) s += We1[d * 256 + h * 64 + o] * ae1[h * 64 + o];
    ce[t] = s;
  } else if (t >= 16 && t < 22) {
    int u = t - 16, d = u / 2, h = u % 2;
    float s = 0.f;
    for (int o = 0; o < 32; o++) s += We2[d * 64 + h * 32 + o] * ae2[h * 32 + o];
    ce[t] = s;
  } else if (t >= 24 && t < 27) {
    int d = t - 24;
    float s = 0.f;
    for (int o = 0; o < 16; o++) s += We3[d * 16 + o] * ae3[o];
    ce[t] = s;
  }
}

__global__ __launch_bounds__(256) void k_scan3(const int* __restrict__ deg,
                                               const int* __restrict__ bsum,
                                               int* __restrict__ rowp) {
  __shared__ int lds[256];
  int t = threadIdx.x;
  int base = blockIdx.x * 1024;
  int v[4];
  int s = 0;
  for (int i = 0; i < 4; i++) {
    int idx = base + t * 4 + i;
    v[i] = (idx < NN) ? deg[idx] + 1 : 0;
    s += v[i];
  }
  lds[t] = s;
  __syncthreads();
  for (int off = 1; off < 256; off <<= 1) {
    int add = (t >= off) ? lds[t - off] : 0;
    __syncthreads();
    lds[t] += add;
    __syncthreads();
  }
  int p = bsum[blockIdx.x] + lds[t] - s;
  for (int i = 0; i < 4; i++) {
    int idx = base + t * 4 + i;
    if (idx < NN) rowp[idx] = p;
    p += v[i];
  }
  if (blockIdx.x == 0 && t == 0) rowp[NN] = NET;
}

// Pure scatter — position known from rowp + rank, no atomics.
__global__ __launch_bounds__(256) void k_place(const int* __restrict__ ei,
                                               const float* __restrict__ ea,
                                               const int* __restrict__ rank,
                                               const int* __restrict__ rowp,
                                               int4* __restrict__ sorted) {
  int e = blockIdx.x * 256 + threadIdx.x;
  if (e >= NE) return;
  int d = ei[NE + e];
  int4 r;
  r.x = ei[e];
  r.y = __float_as_int(ea[3 * (size_t)e + 0]);
  r.z = __float_as_int(ea[3 * (size_t)e + 1]);
  r.w = __float_as_int(ea[3 * (size_t)e + 2]);
  sorted[rowp[d] + rank[e]] = r;
}

// Per-node segment sum of edge_attr over real edges -> mean; write self-loop
// record at rowp[n+1]-1. 16-lane group per node, no atomics.
__global__ __launch_bounds__(256) void k_segloop(const int* __restrict__ rowp,
                                                 int4* __restrict__ sorted) {
  int t = threadIdx.x, g = t >> 4, gl = t & 15;
  int n = blockIdx.x * 16 + g;
  if (n >= NN) return;
  int rp0 = rowp[n], rp1e = rowp[n + 1] - 1;
  float s0 = 0.f, s1 = 0.f, s2 = 0.f;
  for (int j = rp0 + gl; j < rp1e; j += 16) {
    int4 r = sorted[j];
    s0 += __int_as_float(r.y);
    s1 += __int_as_float(r.z);
    s2 += __int_as_float(r.w);
  }
#pragma unroll
  for (int off = 8; off > 0; off >>= 1) {
    s0 += __shfl_xor(s0, off);
    s1 += __shfl_xor(s1, off);
    s2 += __shfl_xor(s2, off);
  }
  if (gl == 0) {
    float inv = 1.f / fmaxf((float)(rp1e - rp0), 1.f);
    int4 r;
    r.x = n;
    r.y = __float_as_int(s0 * inv);
    r.z = __float_as_int(s1 * inv);
    r.w = __float_as_int(s2 * inv);
    sorted[rp1e] = r;
  }
}

// ---------------------------------------------------------------- MFMA GEMM + fused scores
template <int K, int BN, int O, bool AFP32>
__global__ __launch_bounds__(256) void k_gemm_sc(const void* __restrict__ Ap,
                                                 const float* __restrict__ W,
                                                 unsigned short* __restrict__ Cb,
                                                 const float* __restrict__ a_src,
                                                 const float* __restrict__ a_dst,
                                                 float* __restrict__ ssrc,
                                                 float* __restrict__ sdst,
                                                 int M, int NC) {
  constexpr int NT = BN / 16;
  constexpr int HL = BN / O;
  __shared__ unsigned short Wt[BN][K + 8];
  const int t = threadIdx.x;
  const int row0 = blockIdx.x * 64;
  const int col0 = blockIdx.y * BN;
  const int H = NC / O;
  for (int idx = t; idx < BN * K; idx += 256) {
    int c = idx % BN;
    int k = idx / BN;
    Wt[c][k] = f2bf(W[(size_t)k * NC + col0 + c]);
  }
  __syncthreads();
  const int wave = t >> 6, lane = t & 63;
  const int wc = lane & 15;
  const int rbase = row0 + wave * 16 + wc;
  const int kgrp = (lane >> 4) * 8;
  const bool rok = rbase < M;
  f32x4 acc[NT];
#pragma unroll
  for (int i = 0; i < NT; i++) acc[i] = f32x4{0.f, 0.f, 0.f, 0.f};
#pragma unroll
  for (int kk = 0; kk < K; kk += 32) {
    bf16x8 a = {};
    if (rok) {
      if constexpr (AFP32) {
        const float* Af = (const float*)Ap;
        float4 v0 = *(const float4*)(Af + (size_t)rbase * K + kk + kgrp);
        float4 v1 = *(const float4*)(Af + (size_t)rbase * K + kk + kgrp + 4);
        a[0] = (short)f2bf(v0.x); a[1] = (short)f2bf(v0.y);
        a[2] = (short)f2bf(v0.z); a[3] = (short)f2bf(v0.w);
        a[4] = (short)f2bf(v1.x); a[5] = (short)f2bf(v1.y);
        a[6] = (short)f2bf(v1.z); a[7] = (short)f2bf(v1.w);
      } else {
        a = *(const bf16x8*)((const unsigned short*)Ap + (size_t)rbase * K + kk + kgrp);
      }
    }
#pragma unroll
    for (int nt = 0; nt < NT; nt++) {
      bf16x8 b = *(const bf16x8*)(&Wt[nt * 16 + wc][kk + kgrp]);
      acc[nt] = __builtin_amdgcn_mfma_f32_16x16x32_bf16(a, b, acc[nt], 0, 0, 0);
    }
  }
  const int wr0 = row0 + wave * 16 + (lane >> 4) * 4;
  float psrc[4][HL], pdst[4][HL];
#pragma unroll
  for (int i = 0; i < 4; i++)
#pragma unroll
    for (int hl = 0; hl < HL; hl++) { psrc[i][hl] = 0.f; pdst[i][hl] = 0.f; }
#pragma unroll
  for (int nt = 0; nt < NT; nt++) {
    const int col = col0 + nt * 16 + wc;
    const float asv = a_src[col];
    const float adv = a_dst[col];
    const int hl = (nt * 16) / O;
#pragma unroll
    for (int i = 0; i < 4; i++) {
      int r = wr0 + i;
      float v = acc[nt][i];
      if (r < M) Cb[(size_t)r * NC + col] = f2bf(v);
      psrc[i][hl] += v * asv;
      pdst[i][hl] += v * adv;
    }
  }
#pragma unroll
  for (int off = 1; off < 16; off <<= 1)
#pragma unroll
    for (int i = 0; i < 4; i++)
#pragma unroll
      for (int hl = 0; hl < HL; hl++) {
        psrc[i][hl] += __shfl_xor(psrc[i][hl], off);
        pdst[i][hl] += __shfl_xor(pdst[i][hl], off);
      }
  if (wc == 0) {
#pragma unroll
    for (int i = 0; i < 4; i++) {
      int r = wr0 + i;
      if (r < M) {
#pragma unroll
        for (int hl = 0; hl < HL; hl++) {
          int h = col0 / O + hl;
          ssrc[r * H + h] = psrc[i][hl];
          sdst[r * H + h] = pdst[i][hl];
        }
      }
    }
  }
}

// ---------------------------------------------------------------- aggregates

// Layer-1 aggregate: H=4, HO=256, wave/node, 8B/lane gather (R12-verified).
__global__ __launch_bounds__(256) void k_agg_l1(const int4* __restrict__ sorted,
                                                const int* __restrict__ rowp,
                                                const unsigned short* __restrict__ xpb,
                                                const float* __restrict__ ssrc,
                                                const float* __restrict__ sdst,
                                                const float* __restrict__ ce,
                                                const float* __restrict__ bias,
                                                unsigned short* __restrict__ out) {
  constexpr int H = 4;
  __shared__ float lds_p[4][64][H];
  __shared__ int lds_s[4][64];
  const int wave = threadIdx.x >> 6, lane = threadIdx.x & 63;
  const int n = blockIdx.x * 4 + wave;
  if (n >= NN) return;
  const int rp0 = rowp[n], rp1 = rowp[n + 1];
  const int h_lane = lane >> 4;  // (lane*4)/64

  float sd[H], c0[H], c1[H], c2[H];
#pragma unroll
  for (int h = 0; h < H; h++) {
    sd[h] = sdst[n * H + h];
    c0[h] = ce[h];
    c1[h] = ce[H + h];
    c2[h] = ce[2 * H + h];
  }

  float den[H] = {0.f, 0.f, 0.f, 0.f};
  float acc[4] = {0.f, 0.f, 0.f, 0.f};

  for (int cbase = rp0; cbase < rp1; cbase += 64) {
    const int cnt = min(64, rp1 - cbase);
    if (lane < cnt) {
      int4 r = sorted[cbase + lane];
      int s = r.x;
      float e0 = __int_as_float(r.y), e1 = __int_as_float(r.z), e2 = __int_as_float(r.w);
      float4 v = *(const float4*)(ssrc + 4 * (size_t)s);
      float sv[H] = {v.x, v.y, v.z, v.w};
#pragma unroll
      for (int h = 0; h < H; h++) {
        float a = sv[h] + sd[h] + e0 * c0[h] + e1 * c1[h] + e2 * c2[h];
        a = a > 0.f ? a : 0.2f * a;
        float p = __expf(a);
        den[h] += p;
        lds_p[wave][lane][h] = p;
      }
      lds_s[wave][lane] = s;
    }
    for (int c = 0; c < cnt; c++) {
      const float pw = lds_p[wave][c][h_lane];
      const int s = lds_s[wave][c];
      ushort4 u = *(const ushort4*)(xpb + (size_t)s * 256 + lane * 4);
      acc[0] += pw * bf2f(u.x);
      acc[1] += pw * bf2f(u.y);
      acc[2] += pw * bf2f(u.z);
      acc[3] += pw * bf2f(u.w);
    }
  }
#pragma unroll
  for (int off = 32; off > 0; off >>= 1)
#pragma unroll
    for (int h = 0; h < H; h++) den[h] += __shfl_xor(den[h], off);

  const float dinv = 1.f / den[h_lane];
#pragma unroll
  for (int i = 0; i < 4; i++) {
    const int jc = lane * 4 + i;
    float v = acc[i] * dinv + bias[jc];
    v = v > 0.f ? v : __expf(v) - 1.f;  // ELU
    out[(size_t)n * 256 + jc] = f2bf(v);
  }
}

// Layer-2 aggregate: H=2, HO=64 — wave/node, 2 edges/iter (half-wave split,
// ushort2/lane), shfl(32) combine. ELU, bf16 out.
__global__ __launch_bounds__(256) void k_agg_l2(const int4* __restrict__ sorted,
                                                const int* __restrict__ rowp,
                                                const unsigned short* __restrict__ xpb,
                                                const float* __restrict__ ssrc,
                                                const float* __restrict__ sdst,
                                                const float* __restrict__ ce,
                                                const float* __restrict__ bias,
                                                unsigned short* __restrict__ out) {
  __shared__ float lds_p[4][64][2];
  __shared__ int lds_s[4][64];
  const int wave = threadIdx.x >> 6, lane = threadIdx.x & 63;
  const int n = blockIdx.x * 4 + wave;
  if (n >= NN) return;
  const int rp0 = rowp[n], rp1 = rowp[n + 1];
  const int eh = lane >> 5;      // which edge of the pair
  const int cl = lane & 31;      // col pair index: cols cl*2, cl*2+1
  const int h_cl = cl >> 4;      // head of this lane's cols

  float sd0 = sdst[n * 2 + 0], sd1 = sdst[n * 2 + 1];
  float c00 = ce[0], c01 = ce[1], c10 = ce[2], c11 = ce[3], c20 = ce[4], c21 = ce[5];

  float den0 = 0.f, den1 = 0.f;
  float acc0 = 0.f, acc1 = 0.f;

  for (int cbase = rp0; cbase < rp1; cbase += 64) {
    const int cnt = min(64, rp1 - cbase);
    if (lane < cnt) {
      int4 r = sorted[cbase + lane];
      int s = r.x;
      float e0 = __int_as_float(r.y), e1 = __int_as_float(r.z), e2 = __int_as_float(r.w);
      float2 v = *(const float2*)(ssrc + 2 * (size_t)s);
      float a0 = v.x + sd0 + e0 * c00 + e1 * c10 + e2 * c20;
      float a1 = v.y + sd1 + e0 * c01 + e1 * c11 + e2 * c21;
      a0 = a0 > 0.f ? a0 : 0.2f * a0;
      a1 = a1 > 0.f ? a1 : 0.2f * a1;
      float p0 = __expf(a0), p1 = __expf(a1);
      den0 += p0; den1 += p1;
      lds_p[wave][lane][0] = p0;
      lds_p[wave][lane][1] = p1;
      lds_s[wave][lane] = s;
    }
    for (int c = 0; c < cnt; c += 2) {
      const int e = c + eh;
      const bool ok = e < cnt;
      const int ei_ = ok ? e : 0;
      const float pw = ok ? lds_p[wave][ei_][h_cl] : 0.f;
      const int s = lds_s[wave][ei_];
      ushort2 u = *(const ushort2*)(xpb + (size_t)s * 64 + cl * 2);
      acc0 += pw * bf2f(u.x);
      acc1 += pw * bf2f(u.y);
    }
  }
  acc0 += __shfl_xor(acc0, 32);
  acc1 += __shfl_xor(acc1, 32);
#pragma unroll
  for (int off = 32; off > 0; off >>= 1) {
    den0 += __shfl_xor(den0, off);
    den1 += __shfl_xor(den1, off);
  }
  if (eh == 0) {
    const float dinv = 1.f / (h_cl == 0 ? den0 : den1);
    const int col = cl * 2;
    float v0 = acc0 * dinv + bias[col];
    float v1 = acc1 * dinv + bias[col + 1];
    v0 = v0 > 0.f ? v0 : __expf(v0) - 1.f;
    v1 = v1 > 0.f ? v1 : __expf(v1) - 1.f;
    ushort2 o;
    o.x = f2bf(v0); o.y = f2bf(v1);
    *(ushort2*)(out + (size_t)n * 64 + col) = o;
  }
}

// Layer-3 aggregate: HO=16, H=1 — 16-lane groups, single-pass, bf16 gather.
__global__ __launch_bounds__(256) void k_agg3(const int4* __restrict__ sorted,
                                              const int* __restrict__ rowp,
                                              const unsigned short* __restrict__ xpb,
                                              const float* __restrict__ ssrc,
                                              const float* __restrict__ sdst,
                                              const float* __restrict__ ce,
                                              const float* __restrict__ bias,
                                              float* __restrict__ out) {
  __shared__ float lds_p[16][16];
  __shared__ int lds_s[16][16];
  int t = threadIdx.x, g = t >> 4, gl = t & 15;
  int n = blockIdx.x * 16 + g;
  if (n >= NN) return;
  int rp0 = rowp[n], rp1 = rowp[n + 1];
  float sd = sdst[n], ce0 = ce[0], ce1 = ce[1], ce2 = ce[2];

  float den = 0.f, acc = 0.f;
  for (int cbase = rp0; cbase < rp1; cbase += 16) {
    int cnt = min(16, rp1 - cbase);
    if (gl < cnt) {
      int4 r = sorted[cbase + gl];
      float a = ssrc[r.x] + sd + __int_as_float(r.y) * ce0 +
                __int_as_float(r.z) * ce1 + __int_as_float(r.w) * ce2;
      a = a > 0.f ? a : 0.2f * a;
      float p = __expf(a);
      den += p;
      lds_p[g][gl] = p;
      lds_s[g][gl] = r.x;
    }
    for (int c = 0; c < cnt; c++)
      acc += lds_p[g][c] * bf2f(xpb[(size_t)lds_s[g][c] * 16 + gl]);
  }
#pragma unroll
  for (int off = 8; off > 0; off >>= 1) den += __shfl_xor(den, off);
  out[(size_t)n * 16 + gl] = acc / den + bias[gl];
}

// ---------------------------------------------------------------- launch

extern "C" void kernel_launch(void* const* d_in, const int* in_sizes, int n_in,
                              void* d_out, int out_size, void* d_ws, size_t ws_size,
                              hipStream_t stream) {
  const float* x   = (const float*)d_in[0];
  const int*   ei  = (const int*)d_in[1];
  const float* ea  = (const float*)d_in[2];
  const float* W1  = (const float*)d_in[3];
  const float* as1 = (const float*)d_in[4];
  const float* ad1 = (const float*)d_in[5];
  const float* We1 = (const float*)d_in[6];
  const float* ae1 = (const float*)d_in[7];
  const float* b1  = (const float*)d_in[8];
  const float* W2  = (const float*)d_in[9];
  const float* as2 = (const float*)d_in[10];
  const float* ad2 = (const float*)d_in[11];
  const float* We2 = (const float*)d_in[12];
  const float* ae2 = (const float*)d_in[13];
  const float* b2  = (const float*)d_in[14];
  const float* W3  = (const float*)d_in[15];
  const float* as3 = (const float*)d_in[16];
  const float* ad3 = (const float*)d_in[17];
  const float* We3 = (const float*)d_in[18];
  const float* ae3 = (const float*)d_in[19];
  const float* b3  = (const float*)d_in[20];
  float* out = (float*)d_out;

  char* base = (char*)d_ws;
  size_t off = 0;
  auto get = [&](size_t bytes) -> char* {
    char* q = base + off;
    off += (bytes + 255) & ~(size_t)255;
    return q;
  };
  int*   deg    = (int*)get((size_t)NN * 4);
  int*   rank   = (int*)get((size_t)NE * 4);
  int*   rowp   = (int*)get((size_t)(NN + 1) * 4);
  int*   bsum   = (int*)get(256 * 4);
  int4*  sorted = (int4*)get((size_t)NET * 16);
  float* ssrc   = (float*)get((size_t)NN * 16);
  float* sdst   = (float*)get((size_t)NN * 16);
  float* ce     = (float*)get(256);
  unsigned short* xb  = (unsigned short*)get((size_t)NN * 256 * 2);
  unsigned short* h1b = (unsigned short*)get((size_t)NN * 256 * 2);
  unsigned short* h2b = (unsigned short*)get((size_t)NN * 64 * 2);
  (void)ws_size; (void)in_sizes; (void)n_in; (void)out_size;

  hipMemsetAsync(deg, 0, (size_t)NN * 4, stream);

  const int EB = (NE + 255) / 256;
  const int SB = (NN + 1023) / 1024;

  k_rank<<<EB, 256, 0, stream>>>(ei, deg, rank);
  k_scan1<<<SB, 256, 0, stream>>>(deg, bsum);
  k_scan2_ce<<<1, 64, 0, stream>>>(bsum, SB, We1, ae1, We2, ae2, We3, ae3, ce);
  k_scan3<<<SB, 256, 0, stream>>>(deg, bsum, rowp);
  k_place<<<EB, 256, 0, stream>>>(ei, ea, rank, rowp, sorted);
  k_segloop<<<(NN + 15) / 16, 256, 0, stream>>>(rowp, sorted);

  const int GR64 = (NN + 63) / 64;  // 782
  const int AGB = (NN + 3) / 4;     // 12500

  // layer 1: 128 -> 4x64
  k_gemm_sc<128, 64, 64, true><<<dim3(GR64, 4), 256, 0, stream>>>(
      (const void*)x, W1, xb, as1, ad1, ssrc, sdst, NN, 256);
  k_agg_l1<<<AGB, 256, 0, stream>>>(sorted, rowp, xb, ssrc, sdst, ce, b1, h1b);

  // layer 2: 256 -> 2x32
  k_gemm_sc<256, 64, 32, false><<<dim3(GR64, 1), 256, 0, stream>>>(
      (const void*)h1b, W2, xb, as2, ad2, ssrc, sdst, NN, 64);
  k_agg_l2<<<AGB, 256, 0, stream>>>(sorted, rowp, xb, ssrc, sdst, ce + 16, b2, h2b);

  // layer 3: 64 -> 1x16
  k_gemm_sc<64, 16, 16, false><<<dim3(GR64, 1), 256, 0, stream>>>(
      (const void*)h2b, W3, xb, as3, ad3, ssrc, sdst, NN, 16);
  k_agg3<<<(NN + 15) / 16, 256, 0, stream>>>(sorted, rowp, xb, ssrc, sdst, ce + 24, b3, out);
}